// Round 1
// baseline (1944.941 us; speedup 1.0000x reference)
//
#include <hip/hip_runtime.h>
#include <hip/hip_bf16.h>
#include <hip/hip_cooperative_groups.h>

namespace cg = cooperative_groups;

typedef unsigned short u16;
typedef __bf16 bf16x8 __attribute__((ext_vector_type(8)));
typedef float f32x4 __attribute__((ext_vector_type(4)));

#define NB 32      // batch
#define NT 16      // time
#define NN 1000    // nodes
#define NC 16      // in feat
#define NG 32      // gcn out feat
#define NH 512     // hidden
#define NK 32000   // N*G
#define BH (NB*NH) // 16384

__device__ __forceinline__ u16 f2bf(float f) {
    unsigned int u = __float_as_uint(f);
    unsigned int r = u + 0x7FFFu + ((u >> 16) & 1u);
    return (u16)(r >> 16);
}

__device__ __forceinline__ float sigmoidf(float x) { return 1.f / (1.f + __expf(-x)); }

#define GLOAD16(g, l) __builtin_amdgcn_global_load_lds( \
    (const __attribute__((address_space(1))) void*)(g),  \
    (__attribute__((address_space(3))) void*)(l), 16, 0, 0)

// ---------------- graph prep: deg, norm, CSR by dst ----------------
__global__ void graph_prep(const int* __restrict__ ei, const float* __restrict__ ew, int E,
                           int* __restrict__ rowptr, int* __restrict__ csr_src,
                           float* __restrict__ csr_nrm) {
    __shared__ float degs[NN];
    __shared__ float dinv[NN];
    __shared__ int cnt[NN];
    __shared__ int rp[NN + 1];
    int tid = threadIdx.x;
    for (int n = tid; n < NN; n += 1024) { degs[n] = 0.f; cnt[n] = 0; }
    __syncthreads();
    for (int e = tid; e < E; e += 1024) {
        int d = ei[E + e];
        atomicAdd(&degs[d], ew[e]);
        atomicAdd(&cnt[d], 1);
    }
    __syncthreads();
    for (int n = tid; n < NN; n += 1024) {
        float d = degs[n];
        dinv[n] = d > 0.f ? rsqrtf(fmaxf(d, 1e-12f)) : 0.f;
    }
    __syncthreads();
    if (tid == 0) {
        int acc = 0;
        for (int n = 0; n < NN; ++n) { rp[n] = acc; acc += cnt[n]; }
        rp[NN] = acc;
    }
    __syncthreads();
    for (int n = tid; n <= NN; n += 1024) rowptr[n] = rp[n];
    for (int n = tid; n < NN; n += 1024) cnt[n] = 0;
    __syncthreads();
    for (int e = tid; e < E; e += 1024) {
        int d = ei[E + e], s = ei[e];
        int pos = rp[d] + atomicAdd(&cnt[d], 1);
        csr_src[pos] = s;
        csr_nrm[pos] = dinv[s] * ew[e] * dinv[d];
    }
}

// ---------------- xw = einsum('btni,tio->btno') ----------------
__global__ __launch_bounds__(256) void gcn_xw(const float* __restrict__ x,
                                              const float* __restrict__ gw,
                                              float* __restrict__ xw) {
    __shared__ float wt[NC * NG];
    __shared__ float xs[8][NC];
    int bt = blockIdx.y;
    int t = bt & 15;
    int tid = threadIdx.x;
    for (int i = tid; i < NC * NG; i += 256) wt[i] = gw[t * NC * NG + i];
    int n0 = blockIdx.x * 8;
    if (tid < 128) {
        int r = tid >> 4, i = tid & 15;
        xs[r][i] = x[((size_t)bt * NN + n0 + r) * NC + i];
    }
    __syncthreads();
    int g = tid & 31, r = tid >> 5;
    float acc = 0.f;
#pragma unroll
    for (int i = 0; i < NC; ++i) acc += xs[r][i] * wt[i * NG + g];
    xw[((size_t)bt * NN + n0 + r) * NG + g] = acc;
}

// ---------------- agg = A_norm @ xw ; relu(+bias) ; -> bf16 seq ----------------
__global__ __launch_bounds__(256) void gcn_agg(const float* __restrict__ xw,
                                               const int* __restrict__ rowptr,
                                               const int* __restrict__ csr_src,
                                               const float* __restrict__ csr_nrm,
                                               const float* __restrict__ gb,
                                               u16* __restrict__ seq) {
    int bt = blockIdx.y;
    int tid = threadIdx.x;
    int g = tid & 31, r = tid >> 5;
    int n = blockIdx.x * 8 + r;
    int p0 = rowptr[n], p1 = rowptr[n + 1];
    const float* xwbt = xw + (size_t)bt * NK;
    float acc = 0.f;
    for (int p = p0; p < p1; ++p) acc += csr_nrm[p] * xwbt[csr_src[p] * NG + g];
    float h = fmaxf(acc + gb[(bt & 15) * NG + g], 0.f);
    seq[(size_t)bt * NK + n * NG + g] = f2bf(h);
}

// ---------------- w_ih0 fp32 -> bf16 ----------------
__global__ void wconv(const float4* __restrict__ in, ushort4* __restrict__ out, int n4) {
    for (int i = blockIdx.x * blockDim.x + threadIdx.x; i < n4; i += gridDim.x * blockDim.x) {
        float4 v = in[i];
        ushort4 o;
        o.x = f2bf(v.x); o.y = f2bf(v.y); o.z = f2bf(v.z); o.w = f2bf(v.w);
        out[i] = o;
    }
}

// ---------------- big GEMM: part[s] += seq(512xK) @ w16(2048xK)^T, split-K ----------------
// 128x128 tile, BK=64, 4 waves each 64x64 (4x4 frags of 16x16x32), m97 structure.
__global__ __launch_bounds__(256) void gemm_bt(const u16* __restrict__ A,
                                               const u16* __restrict__ Bw,
                                               float* __restrict__ part) {
    __shared__ __align__(16) u16 As[128 * 64];
    __shared__ __align__(16) u16 Bs[128 * 64];
    int tid = threadIdx.x;
    int lane = tid & 63, wid = tid >> 6;
    int wr = wid >> 1, wc = wid & 1;
    int tm = blockIdx.x * 128, tn = blockIdx.y * 128;
    int s = blockIdx.z;
    int ks0 = s * 62 + (s < 4 ? s : 4);
    int ksn = (s < 4) ? 63 : 62;

    int srow = tid >> 3;     // 0..31
    int schunk = tid & 7;    // 0..7

    const u16* ga = A + (size_t)(tm + srow) * NK + (size_t)ks0 * 64 + schunk * 8;
    const u16* gb = Bw + (size_t)(tn + srow) * NK + (size_t)ks0 * 64 + schunk * 8;
    u16* la = As + srow * 64 + schunk * 8;
    u16* lb = Bs + srow * 64 + schunk * 8;

    f32x4 acc[4][4];
#pragma unroll
    for (int i = 0; i < 4; ++i)
#pragma unroll
        for (int j = 0; j < 4; ++j) acc[i][j] = (f32x4){0.f, 0.f, 0.f, 0.f};

    int fr = lane & 15, kq = lane >> 4;
    const u16* arow = As + (wr * 64 + fr) * 64 + kq * 8;
    const u16* brow = Bs + (wc * 64 + fr) * 64 + kq * 8;

    for (int ks = 0; ks < ksn; ++ks) {
        __syncthreads();
#pragma unroll
        for (int q = 0; q < 4; ++q) {
            GLOAD16(ga + (size_t)q * 32 * NK, la + q * 32 * 64);
            GLOAD16(gb + (size_t)q * 32 * NK, lb + q * 32 * 64);
        }
        __syncthreads();
#pragma unroll
        for (int kk = 0; kk < 2; ++kk) {
            bf16x8 af[4], bv[4];
#pragma unroll
            for (int fm = 0; fm < 4; ++fm) af[fm] = *(const bf16x8*)(arow + fm * 1024 + kk * 32);
#pragma unroll
            for (int fn = 0; fn < 4; ++fn) bv[fn] = *(const bf16x8*)(brow + fn * 1024 + kk * 32);
#pragma unroll
            for (int fm = 0; fm < 4; ++fm)
#pragma unroll
                for (int fn = 0; fn < 4; ++fn)
                    acc[fm][fn] = __builtin_amdgcn_mfma_f32_16x16x32_bf16(af[fm], bv[fn], acc[fm][fn], 0, 0, 0);
        }
        ga += 64; gb += 64;
    }

    int rq = lane >> 4;
    size_t base = (size_t)s * 512 * 2048;
#pragma unroll
    for (int fm = 0; fm < 4; ++fm)
#pragma unroll
        for (int fn = 0; fn < 4; ++fn)
#pragma unroll
            for (int rr = 0; rr < 4; ++rr) {
                int m = tm + wr * 64 + fm * 16 + rq * 4 + rr;
                int n = tn + wc * 64 + fn * 16 + (lane & 15);
                part[base + (size_t)m * 2048 + n] = acc[fm][fn][rr];
            }
}

// ---------------- reduce split-K partials + biases -> pre0 ----------------
__global__ void reduce_bias(const float* __restrict__ part, const float* __restrict__ b_ih0,
                            const float* __restrict__ b_hh0, float* __restrict__ pre0) {
    int idx = blockIdx.x * 256 + threadIdx.x;  // < 512*2048
    int n = idx & 2047;
    float a = b_ih0[n] + b_hh0[n];
#pragma unroll
    for (int s = 0; s < 8; ++s) a += part[(size_t)s * 1048576 + idx];
    pre0[idx] = a;
}

__global__ void init_states(float* h0, float* h1, float* c0, float* c1) {
    int i = blockIdx.x * 256 + threadIdx.x;
    if (i < 2 * BH) { h0[i] = 0.f; h1[i] = 0.f; }
    if (i < BH) { c0[i] = 0.f; c1[i] = 0.f; }
}

// ---------------- cooperative fused 2-layer LSTM + projection ----------------
// 256 WGs x 256 threads. WG w owns hidden columns {2w, 2w+1} of both layers.
// thread = (b = tid>>3, idx = tid&7 -> jj=idx&1, q=idx>>1). Layer1 pipelined 1 step behind.
__global__ __launch_bounds__(256) void lstm_coop(const float* __restrict__ pre0,
                                                 const float* __restrict__ w_hh0,
                                                 const float* __restrict__ w_ih1,
                                                 const float* __restrict__ w_hh1,
                                                 const float* __restrict__ b_ih1,
                                                 const float* __restrict__ b_hh1,
                                                 const float* __restrict__ proj_w,
                                                 const float* __restrict__ proj_b,
                                                 float* __restrict__ h0buf,  // 2*BH
                                                 float* __restrict__ c0,
                                                 float* __restrict__ h1buf,  // 2*BH
                                                 float* __restrict__ c1,
                                                 float* __restrict__ out) {
    cg::grid_group grid = cg::this_grid();
    int wg = blockIdx.x, tid = threadIdx.x;
    int b = tid >> 3, idx = tid & 7, jj = idx & 1, q = idx >> 1;
    int j = wg * 2 + jj;
    int row = q * NH + j;
    const float4* w0r = (const float4*)(w_hh0 + (size_t)row * NH);
    const float4* w1r = (const float4*)(w_ih1 + (size_t)row * NH);
    const float4* w2r = (const float4*)(w_hh1 + (size_t)row * NH);
    float bias1 = b_ih1[row] + b_hh1[row];
    __shared__ float gs0[32][8];
    __shared__ float gs1[32][8];

    for (int s = 0; s <= 16; ++s) {
        // ---- layer 0 gate dot (t = s) ----
        if (s < 16) {
            const float4* hp = (const float4*)(h0buf + ((s & 1) ^ 1) * BH + b * NH);
            float acc = pre0[((size_t)(b * NT + s)) * 2048 + row];
#pragma unroll 8
            for (int k = 0; k < NH / 4; ++k) {
                float4 h4 = hp[k], w4 = w0r[k];
                acc += h4.x * w4.x + h4.y * w4.y + h4.z * w4.z + h4.w * w4.w;
            }
            gs0[b][idx] = acc;
        }
        // ---- layer 1 gate dot (t = s-1), independent of this step's layer 0 ----
        if (s >= 1) {
            const float4* xp = (const float4*)(h0buf + ((s - 1) & 1) * BH + b * NH);
            const float4* hp = (const float4*)(h1buf + ((s & 1) ^ 1) * BH + b * NH);
            float acc = bias1;
#pragma unroll 8
            for (int k = 0; k < NH / 4; ++k) {
                float4 x4 = xp[k], w4 = w1r[k];
                acc += x4.x * w4.x + x4.y * w4.y + x4.z * w4.z + x4.w * w4.w;
            }
#pragma unroll 8
            for (int k = 0; k < NH / 4; ++k) {
                float4 h4 = hp[k], w4 = w2r[k];
                acc += h4.x * w4.x + h4.y * w4.y + h4.z * w4.z + h4.w * w4.w;
            }
            gs1[b][idx] = acc;
        }
        __syncthreads();
        // ---- updates (q==0 threads own (b, j)) ----
        if (s < 16 && q == 0) {
            float gi = gs0[b][jj], gf = gs0[b][2 + jj], gg = gs0[b][4 + jj], go = gs0[b][6 + jj];
            float c = sigmoidf(gf) * c0[b * NH + j] + sigmoidf(gi) * tanhf(gg);
            c0[b * NH + j] = c;
            h0buf[(s & 1) * BH + b * NH + j] = sigmoidf(go) * tanhf(c);
        }
        if (s >= 1 && q == 0) {
            float gi = gs1[b][jj], gf = gs1[b][2 + jj], gg = gs1[b][4 + jj], go = gs1[b][6 + jj];
            float c = sigmoidf(gf) * c1[b * NH + j] + sigmoidf(gi) * tanhf(gg);
            c1[b * NH + j] = c;
            h1buf[(s & 1) * BH + b * NH + j] = sigmoidf(go) * tanhf(c);
        }
        grid.sync();
    }

    // projection: final h1 is h1buf parity (16&1)=0
    if (wg == 0) {
        int bb = tid >> 3, o = tid & 7;
        const float* h = h1buf + (size_t)bb * NH;
        float acc = proj_b[o];
        for (int k = 0; k < NH; ++k) acc += h[k] * proj_w[o * NH + k];
        out[bb * 8 + o] = acc;
    }
}

extern "C" void kernel_launch(void* const* d_in, const int* in_sizes, int n_in,
                              void* d_out, int out_size, void* d_ws, size_t ws_size,
                              hipStream_t stream) {
    const float* x      = (const float*)d_in[0];
    const int*   ei     = (const int*)d_in[1];
    const float* ew     = (const float*)d_in[2];
    const float* gcn_w  = (const float*)d_in[3];
    const float* gcn_b  = (const float*)d_in[4];
    const float* w_ih0  = (const float*)d_in[5];
    const float* w_hh0  = (const float*)d_in[6];
    const float* b_ih0  = (const float*)d_in[7];
    const float* b_hh0  = (const float*)d_in[8];
    const float* w_ih1  = (const float*)d_in[9];
    const float* w_hh1  = (const float*)d_in[10];
    const float* b_ih1  = (const float*)d_in[11];
    const float* b_hh1  = (const float*)d_in[12];
    const float* proj_w = (const float*)d_in[13];
    const float* proj_b = (const float*)d_in[14];
    int E = in_sizes[2];

    char* ws = (char*)d_ws;
    size_t off = 0;
    u16* w16      = (u16*)(ws + off);  off += 131072000;         // 2048*32000 bf16
    float* part   = (float*)(ws + off);                          // 8*512*2048 f32 (33.6MB)
    float* xw     = part;              off += 65536000;          // aliases xw (65.5MB)
    u16* seq      = (u16*)(ws + off);  off += 32768000;          // 512*32000 bf16
    float* pre0   = (float*)(ws + off); off += 4194304;          // 512*2048 f32
    float* h0buf  = (float*)(ws + off); off += 2 * BH * 4;
    float* h1buf  = (float*)(ws + off); off += 2 * BH * 4;
    float* c0     = (float*)(ws + off); off += BH * 4;
    float* c1     = (float*)(ws + off); off += BH * 4;
    int* rowptr   = (int*)(ws + off);  off += 4096;
    int* csr_src  = (int*)(ws + off);  off += 36864;
    float* csr_nrm = (float*)(ws + off); off += 36864;
    (void)ws_size; (void)n_in; (void)out_size;

    graph_prep<<<1, 1024, 0, stream>>>(ei, ew, E, rowptr, csr_src, csr_nrm);
    gcn_xw<<<dim3(125, 512), 256, 0, stream>>>(x, gcn_w, xw);
    gcn_agg<<<dim3(125, 512), 256, 0, stream>>>(xw, rowptr, csr_src, csr_nrm, gcn_b, seq);
    wconv<<<8192, 256, 0, stream>>>((const float4*)w_ih0, (ushort4*)w16, 16384000);
    gemm_bt<<<dim3(4, 16, 8), 256, 0, stream>>>(seq, w16, part);
    reduce_bias<<<4096, 256, 0, stream>>>(part, b_ih0, b_hh0, pre0);
    init_states<<<128, 256, 0, stream>>>(h0buf, h1buf, c0, c1);

    float* outf = (float*)d_out;
    void* args[] = { &pre0, &w_hh0, &w_ih1, &w_hh1, &b_ih1, &b_hh1, &proj_w, &proj_b,
                     &h0buf, &c0, &h1buf, &c1, &outf };
    hipLaunchCooperativeKernel((void*)lstm_coop, dim3(256), dim3(256), args, 0, stream);
}

// Round 2
// 1641.561 us; speedup vs baseline: 1.1848x; 1.1848x over previous
//
#include <hip/hip_runtime.h>
#include <hip/hip_bf16.h>
#include <hip/hip_cooperative_groups.h>

namespace cg = cooperative_groups;

typedef unsigned short u16;
typedef __bf16 bf16x8 __attribute__((ext_vector_type(8)));
typedef float f32x4 __attribute__((ext_vector_type(4)));

#define NB 32      // batch
#define NT 16      // time
#define NN 1000    // nodes
#define NC 16      // in feat
#define NG 32      // gcn out feat
#define NH 512     // hidden
#define NK 32000   // N*G
#define BH (NB*NH) // 16384

__device__ __forceinline__ u16 f2bf(float f) {
    unsigned int u = __float_as_uint(f);
    unsigned int r = u + 0x7FFFu + ((u >> 16) & 1u);
    return (u16)(r >> 16);
}

__device__ __forceinline__ float sigmoidf(float x) { return 1.f / (1.f + __expf(-x)); }

__device__ __forceinline__ float dot4(float4 a, float4 b) {
    return a.x * b.x + a.y * b.y + a.z * b.z + a.w * b.w;
}

#define GLOAD16(g, l) __builtin_amdgcn_global_load_lds( \
    (const __attribute__((address_space(1))) void*)(g),  \
    (__attribute__((address_space(3))) void*)(l), 16, 0, 0)

// ---------------- graph prep: deg, norm, CSR by dst ----------------
__global__ void graph_prep(const int* __restrict__ ei, const float* __restrict__ ew, int E,
                           int* __restrict__ rowptr, int* __restrict__ csr_src,
                           float* __restrict__ csr_nrm) {
    __shared__ float degs[NN];
    __shared__ float dinv[NN];
    __shared__ int cnt[NN];
    __shared__ int rp[NN + 1];
    int tid = threadIdx.x;
    for (int n = tid; n < NN; n += 1024) { degs[n] = 0.f; cnt[n] = 0; }
    __syncthreads();
    for (int e = tid; e < E; e += 1024) {
        int d = ei[E + e];
        atomicAdd(&degs[d], ew[e]);
        atomicAdd(&cnt[d], 1);
    }
    __syncthreads();
    for (int n = tid; n < NN; n += 1024) {
        float d = degs[n];
        dinv[n] = d > 0.f ? rsqrtf(fmaxf(d, 1e-12f)) : 0.f;
    }
    __syncthreads();
    if (tid == 0) {
        int acc = 0;
        for (int n = 0; n < NN; ++n) { rp[n] = acc; acc += cnt[n]; }
        rp[NN] = acc;
    }
    __syncthreads();
    for (int n = tid; n <= NN; n += 1024) rowptr[n] = rp[n];
    for (int n = tid; n < NN; n += 1024) cnt[n] = 0;
    __syncthreads();
    for (int e = tid; e < E; e += 1024) {
        int d = ei[E + e], s = ei[e];
        int pos = rp[d] + atomicAdd(&cnt[d], 1);
        csr_src[pos] = s;
        csr_nrm[pos] = dinv[s] * ew[e] * dinv[d];
    }
}

// ---------------- xw = einsum('btni,tio->btno') ----------------
__global__ __launch_bounds__(256) void gcn_xw(const float* __restrict__ x,
                                              const float* __restrict__ gw,
                                              float* __restrict__ xw) {
    __shared__ float wt[NC * NG];
    __shared__ float xs[8][NC];
    int bt = blockIdx.y;
    int t = bt & 15;
    int tid = threadIdx.x;
    for (int i = tid; i < NC * NG; i += 256) wt[i] = gw[t * NC * NG + i];
    int n0 = blockIdx.x * 8;
    if (tid < 128) {
        int r = tid >> 4, i = tid & 15;
        xs[r][i] = x[((size_t)bt * NN + n0 + r) * NC + i];
    }
    __syncthreads();
    int g = tid & 31, r = tid >> 5;
    float acc = 0.f;
#pragma unroll
    for (int i = 0; i < NC; ++i) acc += xs[r][i] * wt[i * NG + g];
    xw[((size_t)bt * NN + n0 + r) * NG + g] = acc;
}

// ---------------- agg = A_norm @ xw ; relu(+bias) ; -> bf16 seq ----------------
__global__ __launch_bounds__(256) void gcn_agg(const float* __restrict__ xw,
                                               const int* __restrict__ rowptr,
                                               const int* __restrict__ csr_src,
                                               const float* __restrict__ csr_nrm,
                                               const float* __restrict__ gb,
                                               u16* __restrict__ seq) {
    int bt = blockIdx.y;
    int tid = threadIdx.x;
    int g = tid & 31, r = tid >> 5;
    int n = blockIdx.x * 8 + r;
    int p0 = rowptr[n], p1 = rowptr[n + 1];
    const float* xwbt = xw + (size_t)bt * NK;
    float acc = 0.f;
    for (int p = p0; p < p1; ++p) acc += csr_nrm[p] * xwbt[csr_src[p] * NG + g];
    float h = fmaxf(acc + gb[(bt & 15) * NG + g], 0.f);
    seq[(size_t)bt * NK + n * NG + g] = f2bf(h);
}

// ---------------- w_ih0 fp32 -> bf16 ----------------
__global__ void wconv(const float4* __restrict__ in, ushort4* __restrict__ out, int n4) {
    for (int i = blockIdx.x * blockDim.x + threadIdx.x; i < n4; i += gridDim.x * blockDim.x) {
        float4 v = in[i];
        ushort4 o;
        o.x = f2bf(v.x); o.y = f2bf(v.y); o.z = f2bf(v.z); o.w = f2bf(v.w);
        out[i] = o;
    }
}

// ---------------- big GEMM: part[s] += seq(512xK) @ w16(2048xK)^T, split-K ----------------
__global__ __launch_bounds__(256) void gemm_bt(const u16* __restrict__ A,
                                               const u16* __restrict__ Bw,
                                               float* __restrict__ part) {
    __shared__ __align__(16) u16 As[128 * 64];
    __shared__ __align__(16) u16 Bs[128 * 64];
    int tid = threadIdx.x;
    int lane = tid & 63, wid = tid >> 6;
    int wr = wid >> 1, wc = wid & 1;
    int tm = blockIdx.x * 128, tn = blockIdx.y * 128;
    int s = blockIdx.z;
    int ks0 = s * 62 + (s < 4 ? s : 4);
    int ksn = (s < 4) ? 63 : 62;

    int srow = tid >> 3;     // 0..31
    int schunk = tid & 7;    // 0..7

    const u16* ga = A + (size_t)(tm + srow) * NK + (size_t)ks0 * 64 + schunk * 8;
    const u16* gb = Bw + (size_t)(tn + srow) * NK + (size_t)ks0 * 64 + schunk * 8;
    u16* la = As + srow * 64 + schunk * 8;
    u16* lb = Bs + srow * 64 + schunk * 8;

    f32x4 acc[4][4];
#pragma unroll
    for (int i = 0; i < 4; ++i)
#pragma unroll
        for (int j = 0; j < 4; ++j) acc[i][j] = (f32x4){0.f, 0.f, 0.f, 0.f};

    int fr = lane & 15, kq = lane >> 4;
    const u16* arow = As + (wr * 64 + fr) * 64 + kq * 8;
    const u16* brow = Bs + (wc * 64 + fr) * 64 + kq * 8;

    for (int ks = 0; ks < ksn; ++ks) {
        __syncthreads();
#pragma unroll
        for (int q = 0; q < 4; ++q) {
            GLOAD16(ga + (size_t)q * 32 * NK, la + q * 32 * 64);
            GLOAD16(gb + (size_t)q * 32 * NK, lb + q * 32 * 64);
        }
        __syncthreads();
#pragma unroll
        for (int kk = 0; kk < 2; ++kk) {
            bf16x8 af[4], bv[4];
#pragma unroll
            for (int fm = 0; fm < 4; ++fm) af[fm] = *(const bf16x8*)(arow + fm * 1024 + kk * 32);
#pragma unroll
            for (int fn = 0; fn < 4; ++fn) bv[fn] = *(const bf16x8*)(brow + fn * 1024 + kk * 32);
#pragma unroll
            for (int fm = 0; fm < 4; ++fm)
#pragma unroll
                for (int fn = 0; fn < 4; ++fn)
                    acc[fm][fn] = __builtin_amdgcn_mfma_f32_16x16x32_bf16(af[fm], bv[fn], acc[fm][fn], 0, 0, 0);
        }
        ga += 64; gb += 64;
    }

    int rq = lane >> 4;
    size_t base = (size_t)s * 512 * 2048;
#pragma unroll
    for (int fm = 0; fm < 4; ++fm)
#pragma unroll
        for (int fn = 0; fn < 4; ++fn)
#pragma unroll
            for (int rr = 0; rr < 4; ++rr) {
                int m = tm + wr * 64 + fm * 16 + rq * 4 + rr;
                int n = tn + wc * 64 + fn * 16 + (lane & 15);
                part[base + (size_t)m * 2048 + n] = acc[fm][fn][rr];
            }
}

// ---------------- reduce split-K partials + biases -> pre0 ----------------
__global__ void reduce_bias(const float* __restrict__ part, const float* __restrict__ b_ih0,
                            const float* __restrict__ b_hh0, float* __restrict__ pre0) {
    int idx = blockIdx.x * 256 + threadIdx.x;  // < 512*2048
    int n = idx & 2047;
    float a = b_ih0[n] + b_hh0[n];
#pragma unroll
    for (int s = 0; s < 8; ++s) a += part[(size_t)s * 1048576 + idx];
    pre0[idx] = a;
}

__global__ void init_states(float* h0, float* h1) {
    int i = blockIdx.x * 256 + threadIdx.x;
    if (i < 2 * BH) { h0[i] = 0.f; h1[i] = 0.f; }
}

// ---------------- cooperative fused 2-layer LSTM + projection ----------------
// 256 WGs x 1024 threads (16 waves). WG owns hidden columns {2wg, 2wg+1} of both layers
// = 8 gate rows per layer. 3 dot tasks per step (all K=512, contiguous-K per wave):
//   dot0 = w_hh0 . h0prev (+pre0)        -> waves 0-7  (gr = wid)
//   dot1 = w_ih1 . h0prev (+bias1)       -> waves 8-15 (gr = wid-8)
//   dot2 = w_hh1 . h1prev, split K-half  -> all 16 waves (gr = wid&7, half = wid>>3)
// Weight rows preloaded to registers once (step-invariant). Full-wave shfl_xor reduce.
// Layer1 pipelined one step behind layer0; one grid.sync per step.
__global__ __launch_bounds__(1024) void lstm_coop(const float* __restrict__ pre0,
                                                  const float* __restrict__ w_hh0,
                                                  const float* __restrict__ w_ih1,
                                                  const float* __restrict__ w_hh1,
                                                  const float* __restrict__ b_ih1,
                                                  const float* __restrict__ b_hh1,
                                                  const float* __restrict__ proj_w,
                                                  const float* __restrict__ proj_b,
                                                  float* __restrict__ h0buf,  // 2*BH
                                                  float* __restrict__ h1buf,  // 2*BH
                                                  float* __restrict__ out) {
    cg::grid_group grid = cg::this_grid();
    int wg = blockIdx.x, tid = threadIdx.x;
    int wid = tid >> 6, lane = tid & 63;
    int gr = wid & 7, half = wid >> 3;
    int row = (gr >> 1) * NH + wg * 2 + (gr & 1);

    __shared__ float ps[4][8][32];   // [slot][gr][b]
    __shared__ float cs[2][64];      // [layer][b*2+jj]

    // preload step-invariant weight rows (contiguous-K per lane)
    const float4* wmain = (const float4*)((half == 0 ? w_hh0 : w_ih1) + (size_t)row * NH);
    float4 wm0 = wmain[lane * 2];
    float4 wm1 = wmain[lane * 2 + 1];
    float4 w2  = ((const float4*)(w_hh1 + (size_t)row * NH))[half * 64 + lane];
    float bias1 = b_ih1[row] + b_hh1[row];

    if (tid < 128) cs[tid >> 6][tid & 63] = 0.f;
    __syncthreads();

    for (int s = 0; s <= 16; ++s) {
        const float* h0p = h0buf + ((s & 1) ^ 1) * BH;   // h0(s-1)
        const float* h1p = h1buf + (s & 1) * BH;          // h1(s-2)

        if (half == 0 && s < 16) {
            // dot0: layer0 gates(t=s)
#pragma unroll 4
            for (int b = 0; b < 32; ++b) {
                const float4* hp = (const float4*)(h0p + b * NH);
                float4 a0 = hp[lane * 2], a1 = hp[lane * 2 + 1];
                float pv = pre0[((size_t)(b * NT + s)) * 2048 + row];
                float p = dot4(a0, wm0) + dot4(a1, wm1);
#pragma unroll
                for (int m = 1; m < 64; m <<= 1) p += __shfl_xor(p, m, 64);
                if (lane == 0) ps[0][gr][b] = p + pv;
            }
        }
        if (half == 1 && s >= 1) {
            // dot1: layer1 x-part (x = h0(s-1))
#pragma unroll 4
            for (int b = 0; b < 32; ++b) {
                const float4* hp = (const float4*)(h0p + b * NH);
                float4 a0 = hp[lane * 2], a1 = hp[lane * 2 + 1];
                float p = dot4(a0, wm0) + dot4(a1, wm1);
#pragma unroll
                for (int m = 1; m < 64; m <<= 1) p += __shfl_xor(p, m, 64);
                if (lane == 0) ps[1][gr][b] = p + bias1;
            }
        }
        if (s >= 1) {
            // dot2: layer1 h-part, K-half per wave group
#pragma unroll 4
            for (int b = 0; b < 32; ++b) {
                float4 a = *(const float4*)(h1p + b * NH + half * 256 + lane * 4);
                float p = dot4(a, w2);
#pragma unroll
                for (int m = 1; m < 64; m <<= 1) p += __shfl_xor(p, m, 64);
                if (lane == 0) ps[2 + half][gr][b] = p;
            }
        }
        __syncthreads();

        if (tid < 64 && s < 16) {
            int b = tid >> 1, jj = tid & 1;
            float gi = ps[0][jj][b],     gf = ps[0][2 + jj][b];
            float gg = ps[0][4 + jj][b], go = ps[0][6 + jj][b];
            float c = sigmoidf(gf) * cs[0][tid] + sigmoidf(gi) * tanhf(gg);
            cs[0][tid] = c;
            h0buf[(s & 1) * BH + b * NH + wg * 2 + jj] = sigmoidf(go) * tanhf(c);
        }
        if (tid >= 64 && tid < 128 && s >= 1) {
            int t2 = tid - 64, b = t2 >> 1, jj = t2 & 1;
            float gi = ps[1][jj][b]     + ps[2][jj][b]     + ps[3][jj][b];
            float gf = ps[1][2 + jj][b] + ps[2][2 + jj][b] + ps[3][2 + jj][b];
            float gg = ps[1][4 + jj][b] + ps[2][4 + jj][b] + ps[3][4 + jj][b];
            float go = ps[1][6 + jj][b] + ps[2][6 + jj][b] + ps[3][6 + jj][b];
            float c = sigmoidf(gf) * cs[1][t2] + sigmoidf(gi) * tanhf(gg);
            cs[1][t2] = c;
            h1buf[((s - 1) & 1) * BH + b * NH + wg * 2 + jj] = sigmoidf(go) * tanhf(c);
        }
        grid.sync();
    }

    // projection: final h1 = h1(15) at parity 1
    if (wg == 0) {
        __shared__ float pj[32][8][4];
        int b = tid >> 5, o = (tid >> 2) & 7, kq = tid & 3;
        const float4* hp = (const float4*)(h1buf + BH + (size_t)b * NH + kq * 128);
        const float4* wp = (const float4*)(proj_w + (size_t)o * NH + kq * 128);
        float acc = 0.f;
#pragma unroll 8
        for (int k = 0; k < 32; ++k) acc += dot4(hp[k], wp[k]);
        pj[b][o][kq] = acc;
        __syncthreads();
        if (tid < 256) {
            int bb = tid >> 3, oo = tid & 7;
            out[bb * 8 + oo] = pj[bb][oo][0] + pj[bb][oo][1] + pj[bb][oo][2] + pj[bb][oo][3] + proj_b[oo];
        }
    }
}

extern "C" void kernel_launch(void* const* d_in, const int* in_sizes, int n_in,
                              void* d_out, int out_size, void* d_ws, size_t ws_size,
                              hipStream_t stream) {
    const float* x      = (const float*)d_in[0];
    const int*   ei     = (const int*)d_in[1];
    const float* ew     = (const float*)d_in[2];
    const float* gcn_w  = (const float*)d_in[3];
    const float* gcn_b  = (const float*)d_in[4];
    const float* w_ih0  = (const float*)d_in[5];
    const float* w_hh0  = (const float*)d_in[6];
    const float* b_ih0  = (const float*)d_in[7];
    const float* b_hh0  = (const float*)d_in[8];
    const float* w_ih1  = (const float*)d_in[9];
    const float* w_hh1  = (const float*)d_in[10];
    const float* b_ih1  = (const float*)d_in[11];
    const float* b_hh1  = (const float*)d_in[12];
    const float* proj_w = (const float*)d_in[13];
    const float* proj_b = (const float*)d_in[14];
    int E = in_sizes[2];

    char* ws = (char*)d_ws;
    size_t off = 0;
    u16* w16      = (u16*)(ws + off);  off += 131072000;         // 2048*32000 bf16
    float* part   = (float*)(ws + off);                          // 8*512*2048 f32
    float* xw     = part;              off += 65536000;          // aliases xw
    u16* seq      = (u16*)(ws + off);  off += 32768000;          // 512*32000 bf16
    float* pre0   = (float*)(ws + off); off += 4194304;          // 512*2048 f32
    float* h0buf  = (float*)(ws + off); off += 2 * BH * 4;
    float* h1buf  = (float*)(ws + off); off += 2 * BH * 4;
    int* rowptr   = (int*)(ws + off);  off += 4096;
    int* csr_src  = (int*)(ws + off);  off += 36864;
    float* csr_nrm = (float*)(ws + off); off += 36864;
    (void)ws_size; (void)n_in; (void)out_size;

    graph_prep<<<1, 1024, 0, stream>>>(ei, ew, E, rowptr, csr_src, csr_nrm);
    gcn_xw<<<dim3(125, 512), 256, 0, stream>>>(x, gcn_w, xw);
    gcn_agg<<<dim3(125, 512), 256, 0, stream>>>(xw, rowptr, csr_src, csr_nrm, gcn_b, seq);
    wconv<<<8192, 256, 0, stream>>>((const float4*)w_ih0, (ushort4*)w16, 16384000);
    gemm_bt<<<dim3(4, 16, 8), 256, 0, stream>>>(seq, w16, part);
    reduce_bias<<<4096, 256, 0, stream>>>(part, b_ih0, b_hh0, pre0);
    init_states<<<128, 256, 0, stream>>>(h0buf, h1buf);

    float* outf = (float*)d_out;
    void* args[] = { &pre0, &w_hh0, &w_ih1, &w_hh1, &b_ih1, &b_hh1, &proj_w, &proj_b,
                     &h0buf, &h1buf, &outf };
    hipLaunchCooperativeKernel((void*)lstm_coop, dim3(256), dim3(1024), args, 0, stream);
}

// Round 4
// 1609.959 us; speedup vs baseline: 1.2081x; 1.0196x over previous
//
#include <hip/hip_runtime.h>
#include <hip/hip_bf16.h>

typedef unsigned short u16;
typedef __bf16 bf16x8 __attribute__((ext_vector_type(8)));
typedef float f32x4 __attribute__((ext_vector_type(4)));

#define NB 32      // batch
#define NT 16      // time
#define NN 1000    // nodes
#define NC 16      // in feat
#define NG 32      // gcn out feat
#define NH 512     // hidden
#define NK 32000   // N*G
#define BH (NB*NH) // 16384
#define NWG 256    // lstm workgroups

__device__ __forceinline__ u16 f2bf(float f) {
    unsigned int u = __float_as_uint(f);
    unsigned int r = u + 0x7FFFu + ((u >> 16) & 1u);
    return (u16)(r >> 16);
}

__device__ __forceinline__ float sigmoidf(float x) { return 1.f / (1.f + __expf(-x)); }

__device__ __forceinline__ float dot4(float4 a, float4 b) {
    return a.x * b.x + a.y * b.y + a.z * b.z + a.w * b.w;
}

#define AT_LOAD(p)    __hip_atomic_load((p), __ATOMIC_RELAXED, __HIP_MEMORY_SCOPE_AGENT)
#define AT_ADD(p, v)  __hip_atomic_fetch_add((p), (v), __ATOMIC_RELAXED, __HIP_MEMORY_SCOPE_AGENT)
#define AT_STORE(p,v) __hip_atomic_store((p), (v), __ATOMIC_RELAXED, __HIP_MEMORY_SCOPE_AGENT)

#define GLOAD16(g, l) __builtin_amdgcn_global_load_lds( \
    (const __attribute__((address_space(1))) void*)(g),  \
    (__attribute__((address_space(3))) void*)(l), 16, 0, 0)

// ---------------- graph prep: deg, norm, CSR by dst ----------------
__global__ void graph_prep(const int* __restrict__ ei, const float* __restrict__ ew, int E,
                           int* __restrict__ rowptr, int* __restrict__ csr_src,
                           float* __restrict__ csr_nrm) {
    __shared__ float degs[NN];
    __shared__ float dinv[NN];
    __shared__ int cnt[NN];
    __shared__ int rp[NN + 1];
    int tid = threadIdx.x;
    for (int n = tid; n < NN; n += 1024) { degs[n] = 0.f; cnt[n] = 0; }
    __syncthreads();
    for (int e = tid; e < E; e += 1024) {
        int d = ei[E + e];
        atomicAdd(&degs[d], ew[e]);
        atomicAdd(&cnt[d], 1);
    }
    __syncthreads();
    for (int n = tid; n < NN; n += 1024) {
        float d = degs[n];
        dinv[n] = d > 0.f ? rsqrtf(fmaxf(d, 1e-12f)) : 0.f;
    }
    __syncthreads();
    if (tid == 0) {
        int acc = 0;
        for (int n = 0; n < NN; ++n) { rp[n] = acc; acc += cnt[n]; }
        rp[NN] = acc;
    }
    __syncthreads();
    for (int n = tid; n <= NN; n += 1024) rowptr[n] = rp[n];
    for (int n = tid; n < NN; n += 1024) cnt[n] = 0;
    __syncthreads();
    for (int e = tid; e < E; e += 1024) {
        int d = ei[E + e], s = ei[e];
        int pos = rp[d] + atomicAdd(&cnt[d], 1);
        csr_src[pos] = s;
        csr_nrm[pos] = dinv[s] * ew[e] * dinv[d];
    }
}

// ---------------- xw = einsum('btni,tio->btno') ----------------
__global__ __launch_bounds__(256) void gcn_xw(const float* __restrict__ x,
                                              const float* __restrict__ gw,
                                              float* __restrict__ xw) {
    __shared__ float wt[NC * NG];
    __shared__ float xs[8][NC];
    int bt = blockIdx.y;
    int t = bt & 15;
    int tid = threadIdx.x;
    for (int i = tid; i < NC * NG; i += 256) wt[i] = gw[t * NC * NG + i];
    int n0 = blockIdx.x * 8;
    if (tid < 128) {
        int r = tid >> 4, i = tid & 15;
        xs[r][i] = x[((size_t)bt * NN + n0 + r) * NC + i];
    }
    __syncthreads();
    int g = tid & 31, r = tid >> 5;
    float acc = 0.f;
#pragma unroll
    for (int i = 0; i < NC; ++i) acc += xs[r][i] * wt[i * NG + g];
    xw[((size_t)bt * NN + n0 + r) * NG + g] = acc;
}

// ---------------- agg = A_norm @ xw ; relu(+bias) ; -> bf16 seq ----------------
__global__ __launch_bounds__(256) void gcn_agg(const float* __restrict__ xw,
                                               const int* __restrict__ rowptr,
                                               const int* __restrict__ csr_src,
                                               const float* __restrict__ csr_nrm,
                                               const float* __restrict__ gb,
                                               u16* __restrict__ seq) {
    int bt = blockIdx.y;
    int tid = threadIdx.x;
    int g = tid & 31, r = tid >> 5;
    int n = blockIdx.x * 8 + r;
    int p0 = rowptr[n], p1 = rowptr[n + 1];
    const float* xwbt = xw + (size_t)bt * NK;
    float acc = 0.f;
    for (int p = p0; p < p1; ++p) acc += csr_nrm[p] * xwbt[csr_src[p] * NG + g];
    float h = fmaxf(acc + gb[(bt & 15) * NG + g], 0.f);
    seq[(size_t)bt * NK + n * NG + g] = f2bf(h);
}

// ---------------- w_ih0 fp32 -> bf16 ----------------
__global__ void wconv(const float4* __restrict__ in, ushort4* __restrict__ out, int n4) {
    for (int i = blockIdx.x * blockDim.x + threadIdx.x; i < n4; i += gridDim.x * blockDim.x) {
        float4 v = in[i];
        ushort4 o;
        o.x = f2bf(v.x); o.y = f2bf(v.y); o.z = f2bf(v.z); o.w = f2bf(v.w);
        out[i] = o;
    }
}

// ---------------- big GEMM: part[s] += seq(512xK) @ w16(2048xK)^T, split-K ----------------
__global__ __launch_bounds__(256) void gemm_bt(const u16* __restrict__ A,
                                               const u16* __restrict__ Bw,
                                               float* __restrict__ part) {
    __shared__ __align__(16) u16 As[128 * 64];
    __shared__ __align__(16) u16 Bs[128 * 64];
    int tid = threadIdx.x;
    int lane = tid & 63, wid = tid >> 6;
    int wr = wid >> 1, wc = wid & 1;
    int tm = blockIdx.x * 128, tn = blockIdx.y * 128;
    int s = blockIdx.z;
    int ks0 = s * 62 + (s < 4 ? s : 4);
    int ksn = (s < 4) ? 63 : 62;

    int srow = tid >> 3;     // 0..31
    int schunk = tid & 7;    // 0..7

    const u16* ga = A + (size_t)(tm + srow) * NK + (size_t)ks0 * 64 + schunk * 8;
    const u16* gb = Bw + (size_t)(tn + srow) * NK + (size_t)ks0 * 64 + schunk * 8;
    u16* la = As + srow * 64 + schunk * 8;
    u16* lb = Bs + srow * 64 + schunk * 8;

    f32x4 acc[4][4];
#pragma unroll
    for (int i = 0; i < 4; ++i)
#pragma unroll
        for (int j = 0; j < 4; ++j) acc[i][j] = (f32x4){0.f, 0.f, 0.f, 0.f};

    int fr = lane & 15, kq = lane >> 4;
    const u16* arow = As + (wr * 64 + fr) * 64 + kq * 8;
    const u16* brow = Bs + (wc * 64 + fr) * 64 + kq * 8;

    for (int ks = 0; ks < ksn; ++ks) {
        __syncthreads();
#pragma unroll
        for (int q = 0; q < 4; ++q) {
            GLOAD16(ga + (size_t)q * 32 * NK, la + q * 32 * 64);
            GLOAD16(gb + (size_t)q * 32 * NK, lb + q * 32 * 64);
        }
        __syncthreads();
#pragma unroll
        for (int kk = 0; kk < 2; ++kk) {
            bf16x8 af[4], bv[4];
#pragma unroll
            for (int fm = 0; fm < 4; ++fm) af[fm] = *(const bf16x8*)(arow + fm * 1024 + kk * 32);
#pragma unroll
            for (int fn = 0; fn < 4; ++fn) bv[fn] = *(const bf16x8*)(brow + fn * 1024 + kk * 32);
#pragma unroll
            for (int fm = 0; fm < 4; ++fm)
#pragma unroll
                for (int fn = 0; fn < 4; ++fn)
                    acc[fm][fn] = __builtin_amdgcn_mfma_f32_16x16x32_bf16(af[fm], bv[fn], acc[fm][fn], 0, 0, 0);
        }
        ga += 64; gb += 64;
    }

    int rq = lane >> 4;
    size_t base = (size_t)s * 512 * 2048;
#pragma unroll
    for (int fm = 0; fm < 4; ++fm)
#pragma unroll
        for (int fn = 0; fn < 4; ++fn)
#pragma unroll
            for (int rr = 0; rr < 4; ++rr) {
                int m = tm + wr * 64 + fm * 16 + rq * 4 + rr;
                int n = tn + wc * 64 + fn * 16 + (lane & 15);
                part[base + (size_t)m * 2048 + n] = acc[fm][fn][rr];
            }
}

// ---------------- reduce split-K partials + biases -> pre0p[s][row][b] ----------------
__global__ __launch_bounds__(256) void reduce_bias_p(const float* __restrict__ part,
                                                     const float* __restrict__ b_ih0,
                                                     const float* __restrict__ b_hh0,
                                                     float* __restrict__ pre0p) {
    int s = blockIdx.y;
    int r = blockIdx.x * 64 + (threadIdx.x & 63);
    int bq = threadIdx.x >> 6;  // 0..3
    float bias = b_ih0[r] + b_hh0[r];
#pragma unroll
    for (int b8 = 0; b8 < 8; ++b8) {
        int b = bq * 8 + b8;
        float acc = bias;
#pragma unroll
        for (int sk = 0; sk < 8; ++sk)
            acc += part[(size_t)sk * 1048576 + (size_t)(b * 16 + s) * 2048 + r];
        pre0p[((size_t)s * 2048 + r) * 32 + b] = acc;
    }
}

__global__ void init_states(float* h0, float* h1, int* bar) {
    int i = blockIdx.x * 256 + threadIdx.x;
    if (i < 2 * BH) { h0[i] = 0.f; h1[i] = 0.f; }
    if (i < 2) bar[i] = 0;
}

// ---------------- lightweight grid barrier ----------------
// h-state is published via agent-scope atomic stores (write-through to coherent
// point), so no L2 writeback is needed at release; arrival/poll is tid0-only;
// acquire fence (cache inv) per thread after the generation flips.
__device__ __forceinline__ void gridbar(int* cnt, int* gen, int target, int tid) {
    __syncthreads();   // drains each wave's vmem (atomic h-stores retired)
    if (tid == 0) {
        int old = AT_ADD(cnt, 1);
        if (old == target * NWG - 1) {
            AT_STORE(gen, target);
        } else {
            while (AT_LOAD(gen) < target) __builtin_amdgcn_s_sleep(8);
        }
    }
    __builtin_amdgcn_fence(__ATOMIC_ACQUIRE, "agent");
    __syncthreads();
}

// ---------------- fused 2-layer LSTM + projection (custom barrier) ----------------
// 256 WGs x 1024 threads. WG owns hidden cols {2wg, 2wg+1} of both layers.
// dot0 = w_hh0 . h0prev          -> waves 0-7
// dot1 = w_ih1 . h0prev          -> waves 8-15
// dot2 = w_hh1 . h1prev (K-half) -> all 16 waves
// pre0/bias adds folded into update phase (coalesced pre0p reads).
__global__ __launch_bounds__(1024) void lstm_coop(const float* __restrict__ pre0p,
                                                  const float* __restrict__ w_hh0,
                                                  const float* __restrict__ w_ih1,
                                                  const float* __restrict__ w_hh1,
                                                  const float* __restrict__ b_ih1,
                                                  const float* __restrict__ b_hh1,
                                                  const float* __restrict__ proj_w,
                                                  const float* __restrict__ proj_b,
                                                  float* __restrict__ h0buf,  // 2*BH
                                                  float* __restrict__ h1buf,  // 2*BH
                                                  int* __restrict__ bar,
                                                  float* __restrict__ out) {
    int wg = blockIdx.x, tid = threadIdx.x;
    int wid = tid >> 6, lane = tid & 63;
    int gr = wid & 7, half = wid >> 3;
    int row = (gr >> 1) * NH + wg * 2 + (gr & 1);

    __shared__ float ps[4][8][32];   // [slot][gr][b]
    __shared__ float cs[2][64];      // [layer][b*2+jj]

    // preload step-invariant weight rows (contiguous-K per lane)
    const float4* wmain = (const float4*)((half == 0 ? w_hh0 : w_ih1) + (size_t)row * NH);
    float4 wm0 = wmain[lane * 2];
    float4 wm1 = wmain[lane * 2 + 1];
    float4 w2  = ((const float4*)(w_hh1 + (size_t)row * NH))[half * 64 + lane];

    // update-thread constants: layer1 biases (threads 64..127)
    float ub0 = 0.f, ub1 = 0.f, ub2 = 0.f, ub3 = 0.f;
    if (tid >= 64 && tid < 128) {
        int jj = (tid - 64) & 1;
        int cj = wg * 2 + jj;
        ub0 = b_ih1[cj] + b_hh1[cj];
        ub1 = b_ih1[NH + cj] + b_hh1[NH + cj];
        ub2 = b_ih1[2 * NH + cj] + b_hh1[2 * NH + cj];
        ub3 = b_ih1[3 * NH + cj] + b_hh1[3 * NH + cj];
    }
    if (tid < 128) cs[tid >> 6][tid & 63] = 0.f;
    __syncthreads();

    for (int s = 0; s <= 16; ++s) {
        const float* h0p = h0buf + ((s & 1) ^ 1) * BH;   // h0(s-1)
        const float* h1p = h1buf + (s & 1) * BH;          // h1(s-2)

        // prefetch pre0p for this step (layer0 update threads, coalesced)
        float up0 = 0.f, up1 = 0.f, up2 = 0.f, up3 = 0.f;
        if (tid < 64 && s < 16) {
            int b = tid >> 1, jj = tid & 1;
            int cj = wg * 2 + jj;
            const float* pp = pre0p + (size_t)s * 2048 * 32 + b;
            up0 = pp[(size_t)cj * 32];
            up1 = pp[((size_t)NH + cj) * 32];
            up2 = pp[((size_t)2 * NH + cj) * 32];
            up3 = pp[((size_t)3 * NH + cj) * 32];
        }

        if (half == 0 && s < 16) {
            // dot0: layer0 recurrent part
#pragma unroll 4
            for (int b = 0; b < 32; ++b) {
                const float4* hp = (const float4*)(h0p + b * NH);
                float4 a0 = hp[lane * 2], a1 = hp[lane * 2 + 1];
                float p = dot4(a0, wm0) + dot4(a1, wm1);
#pragma unroll
                for (int m = 1; m < 64; m <<= 1) p += __shfl_xor(p, m, 64);
                if (lane == 0) ps[0][gr][b] = p;
            }
        }
        if (half == 1 && s >= 1) {
            // dot1: layer1 x-part (x = h0(s-1))
#pragma unroll 4
            for (int b = 0; b < 32; ++b) {
                const float4* hp = (const float4*)(h0p + b * NH);
                float4 a0 = hp[lane * 2], a1 = hp[lane * 2 + 1];
                float p = dot4(a0, wm0) + dot4(a1, wm1);
#pragma unroll
                for (int m = 1; m < 64; m <<= 1) p += __shfl_xor(p, m, 64);
                if (lane == 0) ps[1][gr][b] = p;
            }
        }
        if (s >= 1) {
            // dot2: layer1 h-part, K-half per wave group
#pragma unroll 4
            for (int b = 0; b < 32; ++b) {
                float4 a = *(const float4*)(h1p + b * NH + half * 256 + lane * 4);
                float p = dot4(a, w2);
#pragma unroll
                for (int m = 1; m < 64; m <<= 1) p += __shfl_xor(p, m, 64);
                if (lane == 0) ps[2 + half][gr][b] = p;
            }
        }
        __syncthreads();

        if (tid < 64 && s < 16) {
            int b = tid >> 1, jj = tid & 1;
            float gi = up0 + ps[0][jj][b],     gf = up1 + ps[0][2 + jj][b];
            float gg = up2 + ps[0][4 + jj][b], go = up3 + ps[0][6 + jj][b];
            float c = sigmoidf(gf) * cs[0][tid] + sigmoidf(gi) * tanhf(gg);
            cs[0][tid] = c;
            AT_STORE(&h0buf[(s & 1) * BH + b * NH + wg * 2 + jj], sigmoidf(go) * tanhf(c));
        }
        if (tid >= 64 && tid < 128 && s >= 1) {
            int t2 = tid - 64, b = t2 >> 1, jj = t2 & 1;
            float gi = ub0 + ps[1][jj][b]     + ps[2][jj][b]     + ps[3][jj][b];
            float gf = ub1 + ps[1][2 + jj][b] + ps[2][2 + jj][b] + ps[3][2 + jj][b];
            float gg = ub2 + ps[1][4 + jj][b] + ps[2][4 + jj][b] + ps[3][4 + jj][b];
            float go = ub3 + ps[1][6 + jj][b] + ps[2][6 + jj][b] + ps[3][6 + jj][b];
            float c = sigmoidf(gf) * cs[1][t2] + sigmoidf(gi) * tanhf(gg);
            cs[1][t2] = c;
            AT_STORE(&h1buf[((s - 1) & 1) * BH + b * NH + wg * 2 + jj], sigmoidf(go) * tanhf(c));
        }
        gridbar(&bar[0], &bar[1], s + 1, tid);
    }

    // projection: final h1 = h1(15) at parity 1
    if (wg == 0) {
        __shared__ float pj[32][8][4];
        int b = tid >> 5, o = (tid >> 2) & 7, kq = tid & 3;
        const float4* hp = (const float4*)(h1buf + BH + (size_t)b * NH + kq * 128);
        const float4* wp = (const float4*)(proj_w + (size_t)o * NH + kq * 128);
        float acc = 0.f;
#pragma unroll 8
        for (int k = 0; k < 32; ++k) acc += dot4(hp[k], wp[k]);
        pj[b][o][kq] = acc;
        __syncthreads();
        if (tid < 256) {
            int bb = tid >> 3, oo = tid & 7;
            out[bb * 8 + oo] = pj[bb][oo][0] + pj[bb][oo][1] + pj[bb][oo][2] + pj[bb][oo][3] + proj_b[oo];
        }
    }
}

extern "C" void kernel_launch(void* const* d_in, const int* in_sizes, int n_in,
                              void* d_out, int out_size, void* d_ws, size_t ws_size,
                              hipStream_t stream) {
    const float* x      = (const float*)d_in[0];
    const int*   ei     = (const int*)d_in[1];
    const float* ew     = (const float*)d_in[2];
    const float* gcn_w  = (const float*)d_in[3];
    const float* gcn_b  = (const float*)d_in[4];
    const float* w_ih0  = (const float*)d_in[5];
    const float* w_hh0  = (const float*)d_in[6];
    const float* b_ih0  = (const float*)d_in[7];
    const float* b_hh0  = (const float*)d_in[8];
    const float* w_ih1  = (const float*)d_in[9];
    const float* w_hh1  = (const float*)d_in[10];
    const float* b_ih1  = (const float*)d_in[11];
    const float* b_hh1  = (const float*)d_in[12];
    const float* proj_w = (const float*)d_in[13];
    const float* proj_b = (const float*)d_in[14];
    int E = in_sizes[2];

    char* ws = (char*)d_ws;
    size_t off = 0;
    u16* w16      = (u16*)(ws + off);  off += 131072000;         // 2048*32000 bf16
    float* part   = (float*)(ws + off);                          // 8*512*2048 f32
    float* xw     = part;              off += 65536000;          // aliases xw
    u16* seq      = (u16*)(ws + off);  off += 32768000;          // 512*32000 bf16
    float* pre0p  = (float*)(ws + off); off += 4194304;          // [16][2048][32] f32
    float* h0buf  = (float*)(ws + off); off += 2 * BH * 4;
    float* h1buf  = (float*)(ws + off); off += 2 * BH * 4;
    int* bar      = (int*)(ws + off);  off += 64;
    int* rowptr   = (int*)(ws + off);  off += 4096;
    int* csr_src  = (int*)(ws + off);  off += 36864;
    float* csr_nrm = (float*)(ws + off); off += 36864;
    (void)ws_size; (void)n_in; (void)out_size;

    graph_prep<<<1, 1024, 0, stream>>>(ei, ew, E, rowptr, csr_src, csr_nrm);
    gcn_xw<<<dim3(125, 512), 256, 0, stream>>>(x, gcn_w, xw);
    gcn_agg<<<dim3(125, 512), 256, 0, stream>>>(xw, rowptr, csr_src, csr_nrm, gcn_b, seq);
    wconv<<<8192, 256, 0, stream>>>((const float4*)w_ih0, (ushort4*)w16, 16384000);
    gemm_bt<<<dim3(4, 16, 8), 256, 0, stream>>>(seq, w16, part);
    reduce_bias_p<<<dim3(32, 16), 256, 0, stream>>>(part, b_ih0, b_hh0, pre0p);
    init_states<<<128, 256, 0, stream>>>(h0buf, h1buf, bar);

    float* outf = (float*)d_out;
    lstm_coop<<<NWG, 1024, 0, stream>>>(pre0p, w_hh0, w_ih1, w_hh1, b_ih1, b_hh1,
                                        proj_w, proj_b, h0buf, h1buf, bar, outf);
}

// Round 5
// 763.554 us; speedup vs baseline: 2.5472x; 2.1085x over previous
//
#include <hip/hip_runtime.h>
#include <hip/hip_bf16.h>

typedef unsigned short u16;
typedef __bf16 bf16x8 __attribute__((ext_vector_type(8)));
typedef float f32x4 __attribute__((ext_vector_type(4)));
typedef unsigned short u16x8 __attribute__((ext_vector_type(8)));

#define NB 32      // batch
#define NT 16      // time
#define NN 1000    // nodes
#define NC 16      // in feat
#define NG 32      // gcn out feat
#define NH 512     // hidden
#define NK 32000   // N*G
#define BH (NB*NH) // 16384
#define LWG 64     // lstm workgroups
#define LTH 384    // lstm threads (6 waves)

__device__ __forceinline__ u16 f2bf(float f) {
    unsigned int u = __float_as_uint(f);
    unsigned int r = u + 0x7FFFu + ((u >> 16) & 1u);
    return (u16)(r >> 16);
}

__device__ __forceinline__ float sigmoidf(float x) { return 1.f / (1.f + __expf(-x)); }

__device__ __forceinline__ float dot4(float4 a, float4 b) {
    return a.x * b.x + a.y * b.y + a.z * b.z + a.w * b.w;
}

#define AT_LOAD(p)    __hip_atomic_load((p), __ATOMIC_RELAXED, __HIP_MEMORY_SCOPE_AGENT)
#define AT_STORE(p,v) __hip_atomic_store((p), (v), __ATOMIC_RELAXED, __HIP_MEMORY_SCOPE_AGENT)

#define GLOAD16(g, l) __builtin_amdgcn_global_load_lds( \
    (const __attribute__((address_space(1))) void*)(g),  \
    (__attribute__((address_space(3))) void*)(l), 16, 0, 0)

// ---------------- graph prep: deg, norm, CSR by dst ----------------
__global__ void graph_prep(const int* __restrict__ ei, const float* __restrict__ ew, int E,
                           int* __restrict__ rowptr, int* __restrict__ csr_src,
                           float* __restrict__ csr_nrm) {
    __shared__ float degs[NN];
    __shared__ float dinv[NN];
    __shared__ int cnt[NN];
    __shared__ int rp[NN + 1];
    int tid = threadIdx.x;
    for (int n = tid; n < NN; n += 1024) { degs[n] = 0.f; cnt[n] = 0; }
    __syncthreads();
    for (int e = tid; e < E; e += 1024) {
        int d = ei[E + e];
        atomicAdd(&degs[d], ew[e]);
        atomicAdd(&cnt[d], 1);
    }
    __syncthreads();
    for (int n = tid; n < NN; n += 1024) {
        float d = degs[n];
        dinv[n] = d > 0.f ? rsqrtf(fmaxf(d, 1e-12f)) : 0.f;
    }
    __syncthreads();
    if (tid == 0) {
        int acc = 0;
        for (int n = 0; n < NN; ++n) { rp[n] = acc; acc += cnt[n]; }
        rp[NN] = acc;
    }
    __syncthreads();
    for (int n = tid; n <= NN; n += 1024) rowptr[n] = rp[n];
    for (int n = tid; n < NN; n += 1024) cnt[n] = 0;
    __syncthreads();
    for (int e = tid; e < E; e += 1024) {
        int d = ei[E + e], s = ei[e];
        int pos = rp[d] + atomicAdd(&cnt[d], 1);
        csr_src[pos] = s;
        csr_nrm[pos] = dinv[s] * ew[e] * dinv[d];
    }
}

// ---------------- xw = einsum('btni,tio->btno') ----------------
__global__ __launch_bounds__(256) void gcn_xw(const float* __restrict__ x,
                                              const float* __restrict__ gw,
                                              float* __restrict__ xw) {
    __shared__ float wt[NC * NG];
    __shared__ float xs[8][NC];
    int bt = blockIdx.y;
    int t = bt & 15;
    int tid = threadIdx.x;
    for (int i = tid; i < NC * NG; i += 256) wt[i] = gw[t * NC * NG + i];
    int n0 = blockIdx.x * 8;
    if (tid < 128) {
        int r = tid >> 4, i = tid & 15;
        xs[r][i] = x[((size_t)bt * NN + n0 + r) * NC + i];
    }
    __syncthreads();
    int g = tid & 31, r = tid >> 5;
    float acc = 0.f;
#pragma unroll
    for (int i = 0; i < NC; ++i) acc += xs[r][i] * wt[i * NG + g];
    xw[((size_t)bt * NN + n0 + r) * NG + g] = acc;
}

// ---------------- agg = A_norm @ xw ; relu(+bias) ; -> bf16 seq ----------------
__global__ __launch_bounds__(256) void gcn_agg(const float* __restrict__ xw,
                                               const int* __restrict__ rowptr,
                                               const int* __restrict__ csr_src,
                                               const float* __restrict__ csr_nrm,
                                               const float* __restrict__ gb,
                                               u16* __restrict__ seq) {
    int bt = blockIdx.y;
    int tid = threadIdx.x;
    int g = tid & 31, r = tid >> 5;
    int n = blockIdx.x * 8 + r;
    int p0 = rowptr[n], p1 = rowptr[n + 1];
    const float* xwbt = xw + (size_t)bt * NK;
    float acc = 0.f;
    for (int p = p0; p < p1; ++p) acc += csr_nrm[p] * xwbt[csr_src[p] * NG + g];
    float h = fmaxf(acc + gb[(bt & 15) * NG + g], 0.f);
    seq[(size_t)bt * NK + n * NG + g] = f2bf(h);
}

// ---------------- w_ih0 fp32 -> bf16 ----------------
__global__ void wconv(const float4* __restrict__ in, ushort4* __restrict__ out, int n4) {
    for (int i = blockIdx.x * blockDim.x + threadIdx.x; i < n4; i += gridDim.x * blockDim.x) {
        float4 v = in[i];
        ushort4 o;
        o.x = f2bf(v.x); o.y = f2bf(v.y); o.z = f2bf(v.z); o.w = f2bf(v.w);
        out[i] = o;
    }
}

// ---------------- big GEMM: part[s] += seq(512xK) @ w16(2048xK)^T, split-K ----------------
__global__ __launch_bounds__(256) void gemm_bt(const u16* __restrict__ A,
                                               const u16* __restrict__ Bw,
                                               float* __restrict__ part) {
    __shared__ __align__(16) u16 As[128 * 64];
    __shared__ __align__(16) u16 Bs[128 * 64];
    int tid = threadIdx.x;
    int lane = tid & 63, wid = tid >> 6;
    int wr = wid >> 1, wc = wid & 1;
    int tm = blockIdx.x * 128, tn = blockIdx.y * 128;
    int s = blockIdx.z;
    int ks0 = s * 62 + (s < 4 ? s : 4);
    int ksn = (s < 4) ? 63 : 62;

    int srow = tid >> 3;     // 0..31
    int schunk = tid & 7;    // 0..7

    const u16* ga = A + (size_t)(tm + srow) * NK + (size_t)ks0 * 64 + schunk * 8;
    const u16* gb = Bw + (size_t)(tn + srow) * NK + (size_t)ks0 * 64 + schunk * 8;
    u16* la = As + srow * 64 + schunk * 8;
    u16* lb = Bs + srow * 64 + schunk * 8;

    f32x4 acc[4][4];
#pragma unroll
    for (int i = 0; i < 4; ++i)
#pragma unroll
        for (int j = 0; j < 4; ++j) acc[i][j] = (f32x4){0.f, 0.f, 0.f, 0.f};

    int fr = lane & 15, kq = lane >> 4;
    const u16* arow = As + (wr * 64 + fr) * 64 + kq * 8;
    const u16* brow = Bs + (wc * 64 + fr) * 64 + kq * 8;

    for (int ks = 0; ks < ksn; ++ks) {
        __syncthreads();
#pragma unroll
        for (int q = 0; q < 4; ++q) {
            GLOAD16(ga + (size_t)q * 32 * NK, la + q * 32 * 64);
            GLOAD16(gb + (size_t)q * 32 * NK, lb + q * 32 * 64);
        }
        __syncthreads();
#pragma unroll
        for (int kk = 0; kk < 2; ++kk) {
            bf16x8 af[4], bv[4];
#pragma unroll
            for (int fm = 0; fm < 4; ++fm) af[fm] = *(const bf16x8*)(arow + fm * 1024 + kk * 32);
#pragma unroll
            for (int fn = 0; fn < 4; ++fn) bv[fn] = *(const bf16x8*)(brow + fn * 1024 + kk * 32);
#pragma unroll
            for (int fm = 0; fm < 4; ++fm)
#pragma unroll
                for (int fn = 0; fn < 4; ++fn)
                    acc[fm][fn] = __builtin_amdgcn_mfma_f32_16x16x32_bf16(af[fm], bv[fn], acc[fm][fn], 0, 0, 0);
        }
        ga += 64; gb += 64;
    }

    int rq = lane >> 4;
    size_t base = (size_t)s * 512 * 2048;
#pragma unroll
    for (int fm = 0; fm < 4; ++fm)
#pragma unroll
        for (int fn = 0; fn < 4; ++fn)
#pragma unroll
            for (int rr = 0; rr < 4; ++rr) {
                int m = tm + wr * 64 + fm * 16 + rq * 4 + rr;
                int n = tn + wc * 64 + fn * 16 + (lane & 15);
                part[base + (size_t)m * 2048 + n] = acc[fm][fn][rr];
            }
}

// ---------------- reduce split-K partials + biases -> pre0p[s][row][b] ----------------
__global__ __launch_bounds__(256) void reduce_bias_p(const float* __restrict__ part,
                                                     const float* __restrict__ b_ih0,
                                                     const float* __restrict__ b_hh0,
                                                     float* __restrict__ pre0p) {
    int s = blockIdx.y;
    int r = blockIdx.x * 64 + (threadIdx.x & 63);
    int bq = threadIdx.x >> 6;  // 0..3
    float bias = b_ih0[r] + b_hh0[r];
#pragma unroll
    for (int b8 = 0; b8 < 8; ++b8) {
        int b = bq * 8 + b8;
        float acc = bias;
#pragma unroll
        for (int sk = 0; sk < 8; ++sk)
            acc += part[(size_t)sk * 1048576 + (size_t)(b * 16 + s) * 2048 + r];
        pre0p[((size_t)s * 2048 + r) * 32 + b] = acc;
    }
}

// ---------------- weight permute: frag-blocked bf16 Wbig[wg][rt][kt][lane][8] ----------------
// WG wg owns cols [wg*8, wg*8+8). Row p in [0,96): p<32 -> w_hh0 gate (p>>3) col (p&7);
// p in [32,64) -> w_ih1; p in [64,96) -> w_hh1. Within a (rt,kt) block, lane's 8 bf16 =
// src row (rt*16 + (lane&15)), k = kt*32 + (lane>>4)*8 .. +8  (exact MFMA A-frag order).
__global__ __launch_bounds__(256) void wperm(const float* __restrict__ w_hh0,
                                             const float* __restrict__ w_ih1,
                                             const float* __restrict__ w_hh1,
                                             u16* __restrict__ Wbig) {
    int rt = blockIdx.x;   // 0..5
    int wg = blockIdx.y;   // 0..63
    int tid = threadIdx.x;
#pragma unroll
    for (int it = 0; it < 4; ++it) {
        int idx = it * 256 + tid;           // 0..1023
        int kt = idx >> 6, lane = idx & 63;
        int p = rt * 16 + (lane & 15);
        int gate = (p & 31) >> 3;
        int col = wg * 8 + (p & 7);
        const float* src;
        if (p < 32)      src = w_hh0 + (size_t)(gate * NH + col) * NH;
        else if (p < 64) src = w_ih1 + (size_t)(gate * NH + col) * NH;
        else             src = w_hh1 + (size_t)(gate * NH + col) * NH;
        int k0 = kt * 32 + (lane >> 4) * 8;
        float4 v0 = *(const float4*)(src + k0);
        float4 v1 = *(const float4*)(src + k0 + 4);
        u16x8 o;
        o[0] = f2bf(v0.x); o[1] = f2bf(v0.y); o[2] = f2bf(v0.z); o[3] = f2bf(v0.w);
        o[4] = f2bf(v1.x); o[5] = f2bf(v1.y); o[6] = f2bf(v1.z); o[7] = f2bf(v1.w);
        *(u16x8*)(Wbig + (((size_t)wg * 6 + rt) * 16 + kt) * 512 + lane * 8) = o;
    }
}

__global__ void init2(u16* h0, u16* h1, int* flags) {
    int i = blockIdx.x * 256 + threadIdx.x;
    if (i < 2 * BH) { h0[i] = 0; h1[i] = 0; }
    if (i < 1024) flags[i] = 0;
}

// ---------------- persistent MFMA LSTM: 64 WGs x 384 thr, weights in LDS ----------------
// Wave wid handles row-tile rt=wid of the WG's 96 permuted rows (grp = wid>>1: 0=G0
// w_hh0·h0, 1=G1 w_ih1·h0, 2=G2 w_hh1·h1). h stored bf16 [b][512] global, double-buffered.
// Per step: MFMA (A from LDS, B from global h) -> G LDS -> gate update (c in LDS) ->
// bf16 h pack (wave 0) -> flag barrier (all-poll-all, 64 flag lines).
__global__ __launch_bounds__(LTH) void lstm2(const u16* __restrict__ Wbig,
                                             const float* __restrict__ pre0p,
                                             const float* __restrict__ b_ih1,
                                             const float* __restrict__ b_hh1,
                                             u16* __restrict__ h0buf,   // 2*BH bf16
                                             u16* __restrict__ h1buf,   // 2*BH bf16
                                             float* __restrict__ h1f,   // BH fp32 (final)
                                             int* __restrict__ flags) {
    __shared__ __align__(16) u16 Wlds[96 * 512];   // 96KB, frag-blocked [rt][kt][lane][8]
    __shared__ float G[96][33];                    // gate outputs, padded
    __shared__ float cst[2][8][32];                // c-state [layer][col][b]
    __shared__ u16 hst[2][8][32];                  // h bf16 staging
    int wg = blockIdx.x, tid = threadIdx.x;
    int wid = tid >> 6, lane = tid & 63;
    int grp = wid >> 1;

    // stage weights global->LDS (linear, 16 iters x 384 thr x 16B)
#pragma unroll
    for (int it = 0; it < 16; ++it)
        GLOAD16(Wbig + (size_t)wg * 49152 + it * 3072 + tid * 8, Wlds + it * 3072 + tid * 8);

    // init c-state
    if (tid < 512) ((float*)cst)[tid] = 0.f;

    // update-thread constants
    int uj = (tid >> 5) & 7, ub = tid & 31;
    int ucol = wg * 8 + uj;
    float bs0 = 0.f, bs1 = 0.f, bs2 = 0.f, bs3 = 0.f;
    if (tid < 256) {
        bs0 = b_ih1[ucol] + b_hh1[ucol];
        bs1 = b_ih1[NH + ucol] + b_hh1[NH + ucol];
        bs2 = b_ih1[2 * NH + ucol] + b_hh1[2 * NH + ucol];
        bs3 = b_ih1[3 * NH + ucol] + b_hh1[3 * NH + ucol];
    }
    __syncthreads();   // weights staged (barrier drains vmcnt), c ready

    const u16* wbase = Wlds + wid * 16 * 512 + lane * 8;

    for (int s = 0; s <= 16; ++s) {
        bool active = (grp == 0) ? (s < 16) : (s >= 1);
        if (active) {
            const u16* hb = (grp < 2) ? (h0buf + ((s & 1) ^ 1) * BH)
                                      : (h1buf + (s & 1) * BH);
            const u16* hp0 = hb + (lane & 15) * 512 + (lane >> 4) * 8;
            const u16* hp1 = hp0 + 16 * 512;
            f32x4 a0 = (f32x4){0.f, 0.f, 0.f, 0.f};
            f32x4 a1 = (f32x4){0.f, 0.f, 0.f, 0.f};
#pragma unroll
            for (int kt = 0; kt < 16; ++kt) {
                bf16x8 af = *(const bf16x8*)(wbase + kt * 512);
                bf16x8 b0 = *(const bf16x8*)(hp0 + kt * 32);
                bf16x8 b1 = *(const bf16x8*)(hp1 + kt * 32);
                a0 = __builtin_amdgcn_mfma_f32_16x16x32_bf16(af, b0, a0, 0, 0, 0);
                a1 = __builtin_amdgcn_mfma_f32_16x16x32_bf16(af, b1, a1, 0, 0, 0);
            }
            int r0 = wid * 16 + (lane >> 4) * 4;
#pragma unroll
            for (int rr = 0; rr < 4; ++rr) {
                G[r0 + rr][lane & 15] = a0[rr];
                G[r0 + rr][16 + (lane & 15)] = a1[rr];
            }
        }
        __syncthreads();

        if (tid < 256) {
            if (s < 16) {  // layer 0 update
                const float* pp = pre0p + (size_t)s * 2048 * 32 + ub;
                float gi = G[uj][ub]      + pp[(size_t)(ucol) * 32];
                float gf = G[8 + uj][ub]  + pp[(size_t)(NH + ucol) * 32];
                float gg = G[16 + uj][ub] + pp[(size_t)(2 * NH + ucol) * 32];
                float go = G[24 + uj][ub] + pp[(size_t)(3 * NH + ucol) * 32];
                float c = sigmoidf(gf) * cst[0][uj][ub] + sigmoidf(gi) * tanhf(gg);
                cst[0][uj][ub] = c;
                hst[0][uj][ub] = f2bf(sigmoidf(go) * tanhf(c));
            }
            if (s >= 1) {  // layer 1 update (t = s-1)
                float gi = G[32 + uj][ub] + G[64 + uj][ub] + bs0;
                float gf = G[40 + uj][ub] + G[72 + uj][ub] + bs1;
                float gg = G[48 + uj][ub] + G[80 + uj][ub] + bs2;
                float go = G[56 + uj][ub] + G[88 + uj][ub] + bs3;
                float c = sigmoidf(gf) * cst[1][uj][ub] + sigmoidf(gi) * tanhf(gg);
                cst[1][uj][ub] = c;
                float hv = sigmoidf(go) * tanhf(c);
                hst[1][uj][ub] = f2bf(hv);
                if (s == 16) h1f[ub * NH + ucol] = hv;
            }
        }
        __syncthreads();

        // pack h (wave 0): 16B per batch row
        if (tid < 32 && s < 16) {
            u16x8 v;
#pragma unroll
            for (int j = 0; j < 8; ++j) v[j] = hst[0][j][tid];
            *(u16x8*)(h0buf + (s & 1) * BH + tid * 512 + wg * 8) = v;
        }
        if (tid >= 32 && tid < 64 && s >= 1) {
            int b = tid - 32;
            u16x8 v;
#pragma unroll
            for (int j = 0; j < 8; ++j) v[j] = hst[1][j][b];
            *(u16x8*)(h1buf + ((s - 1) & 1) * BH + b * 512 + wg * 8) = v;
        }

        // ---- flag barrier ----
        __syncthreads();
        if (wid == 0) {
            __builtin_amdgcn_fence(__ATOMIC_RELEASE, "agent");  // drain wave0's h stores
            if (lane == 0) AT_STORE(&flags[wg * 16], s + 1);
            int target = s + 1;
            for (;;) {
                int v = AT_LOAD(&flags[lane * 16]);
                if (__all(v >= target)) break;
                __builtin_amdgcn_s_sleep(2);
            }
        }
        __builtin_amdgcn_fence(__ATOMIC_ACQUIRE, "agent");
        __syncthreads();
    }
}

// ---------------- projection from fp32 final h1 ----------------
__global__ __launch_bounds__(1024) void proj_k(const float* __restrict__ h1f,
                                               const float* __restrict__ proj_w,
                                               const float* __restrict__ proj_b,
                                               float* __restrict__ out) {
    __shared__ float pj[32][8][4];
    int tid = threadIdx.x;
    int b = tid >> 5, o = (tid >> 2) & 7, kq = tid & 3;
    const float4* hp = (const float4*)(h1f + (size_t)b * NH + kq * 128);
    const float4* wp = (const float4*)(proj_w + (size_t)o * NH + kq * 128);
    float acc = 0.f;
#pragma unroll 8
    for (int k = 0; k < 32; ++k) acc += dot4(hp[k], wp[k]);
    pj[b][o][kq] = acc;
    __syncthreads();
    if (tid < 256) {
        int bb = tid >> 3, oo = tid & 7;
        out[bb * 8 + oo] = pj[bb][oo][0] + pj[bb][oo][1] + pj[bb][oo][2] + pj[bb][oo][3] + proj_b[oo];
    }
}

extern "C" void kernel_launch(void* const* d_in, const int* in_sizes, int n_in,
                              void* d_out, int out_size, void* d_ws, size_t ws_size,
                              hipStream_t stream) {
    const float* x      = (const float*)d_in[0];
    const int*   ei     = (const int*)d_in[1];
    const float* ew     = (const float*)d_in[2];
    const float* gcn_w  = (const float*)d_in[3];
    const float* gcn_b  = (const float*)d_in[4];
    const float* w_ih0  = (const float*)d_in[5];
    const float* w_hh0  = (const float*)d_in[6];
    const float* b_ih0  = (const float*)d_in[7];
    const float* b_hh0  = (const float*)d_in[8];
    const float* w_ih1  = (const float*)d_in[9];
    const float* w_hh1  = (const float*)d_in[10];
    const float* b_ih1  = (const float*)d_in[11];
    const float* b_hh1  = (const float*)d_in[12];
    const float* proj_w = (const float*)d_in[13];
    const float* proj_b = (const float*)d_in[14];
    int E = in_sizes[2];

    char* ws = (char*)d_ws;
    size_t off = 0;
    u16* w16      = (u16*)(ws + off);  off += 131072000;         // 2048*32000 bf16
    float* part   = (float*)(ws + off);                          // 8*512*2048 f32
    float* xw     = part;                                        // aliases part
    u16* Wbig     = (u16*)part;        off += 65536000;          // aliases part (6.3MB, after reduce)
    u16* seq      = (u16*)(ws + off);  off += 32768000;          // 512*32000 bf16
    float* pre0p  = (float*)(ws + off); off += 4194304;          // [16][2048][32] f32
    u16* h0buf    = (u16*)(ws + off);  off += 2 * BH * 2;
    u16* h1buf    = (u16*)(ws + off);  off += 2 * BH * 2;
    float* h1f    = (float*)(ws + off); off += BH * 4;
    int* flags    = (int*)(ws + off);  off += 4096;
    int* rowptr   = (int*)(ws + off);  off += 4096;
    int* csr_src  = (int*)(ws + off);  off += 36864;
    float* csr_nrm = (float*)(ws + off); off += 36864;
    (void)ws_size; (void)n_in; (void)out_size;

    graph_prep<<<1, 1024, 0, stream>>>(ei, ew, E, rowptr, csr_src, csr_nrm);
    gcn_xw<<<dim3(125, 512), 256, 0, stream>>>(x, gcn_w, xw);
    gcn_agg<<<dim3(125, 512), 256, 0, stream>>>(xw, rowptr, csr_src, csr_nrm, gcn_b, seq);
    wconv<<<8192, 256, 0, stream>>>((const float4*)w_ih0, (ushort4*)w16, 16384000);
    gemm_bt<<<dim3(4, 16, 8), 256, 0, stream>>>(seq, w16, part);
    reduce_bias_p<<<dim3(32, 16), 256, 0, stream>>>(part, b_ih0, b_hh0, pre0p);
    // part is now consumed -> its region hosts Wbig
    wperm<<<dim3(6, 64), 256, 0, stream>>>(w_hh0, w_ih1, w_hh1, Wbig);
    init2<<<128, 256, 0, stream>>>(h0buf, h1buf, flags);

    lstm2<<<LWG, LTH, 0, stream>>>(Wbig, pre0p, b_ih1, b_hh1, h0buf, h1buf, h1f, flags);
    proj_k<<<1, 1024, 0, stream>>>(h1f, proj_w, proj_b, (float*)d_out);
}

// Round 6
// 600.984 us; speedup vs baseline: 3.2363x; 1.2705x over previous
//
#include <hip/hip_runtime.h>
#include <hip/hip_bf16.h>

typedef unsigned short u16;
typedef __bf16 bf16x8 __attribute__((ext_vector_type(8)));
typedef float f32x4 __attribute__((ext_vector_type(4)));
typedef unsigned short u16x8 __attribute__((ext_vector_type(8)));

#define NB 32      // batch
#define NT 16      // time
#define NN 1000    // nodes
#define NC 16      // in feat
#define NG 32      // gcn out feat
#define NH 512     // hidden
#define NK 32000   // N*G
#define BH (NB*NH) // 16384
#define LWG 64     // lstm workgroups
#define LTH 384    // lstm threads (6 waves)

__device__ __forceinline__ u16 f2bf(float f) {
    unsigned int u = __float_as_uint(f);
    unsigned int r = u + 0x7FFFu + ((u >> 16) & 1u);
    return (u16)(r >> 16);
}

__device__ __forceinline__ float sigmoidf(float x) { return 1.f / (1.f + __expf(-x)); }

__device__ __forceinline__ float dot4(float4 a, float4 b) {
    return a.x * b.x + a.y * b.y + a.z * b.z + a.w * b.w;
}

#define AT_LOAD(p)    __hip_atomic_load((p), __ATOMIC_RELAXED, __HIP_MEMORY_SCOPE_AGENT)
#define AT_STORE(p,v) __hip_atomic_store((p), (v), __ATOMIC_RELAXED, __HIP_MEMORY_SCOPE_AGENT)

#define GLOAD16(g, l) __builtin_amdgcn_global_load_lds( \
    (const __attribute__((address_space(1))) void*)(g),  \
    (__attribute__((address_space(3))) void*)(l), 16, 0, 0)

// ---------------- graph prep: deg, norm, CSR by dst ----------------
__global__ void graph_prep(const int* __restrict__ ei, const float* __restrict__ ew, int E,
                           int* __restrict__ rowptr, int* __restrict__ csr_src,
                           float* __restrict__ csr_nrm) {
    __shared__ float degs[NN];
    __shared__ float dinv[NN];
    __shared__ int cnt[NN];
    __shared__ int rp[NN + 1];
    int tid = threadIdx.x;
    for (int n = tid; n < NN; n += 1024) { degs[n] = 0.f; cnt[n] = 0; }
    __syncthreads();
    for (int e = tid; e < E; e += 1024) {
        int d = ei[E + e];
        atomicAdd(&degs[d], ew[e]);
        atomicAdd(&cnt[d], 1);
    }
    __syncthreads();
    for (int n = tid; n < NN; n += 1024) {
        float d = degs[n];
        dinv[n] = d > 0.f ? rsqrtf(fmaxf(d, 1e-12f)) : 0.f;
    }
    __syncthreads();
    if (tid == 0) {
        int acc = 0;
        for (int n = 0; n < NN; ++n) { rp[n] = acc; acc += cnt[n]; }
        rp[NN] = acc;
    }
    __syncthreads();
    for (int n = tid; n <= NN; n += 1024) rowptr[n] = rp[n];
    for (int n = tid; n < NN; n += 1024) cnt[n] = 0;
    __syncthreads();
    for (int e = tid; e < E; e += 1024) {
        int d = ei[E + e], s = ei[e];
        int pos = rp[d] + atomicAdd(&cnt[d], 1);
        csr_src[pos] = s;
        csr_nrm[pos] = dinv[s] * ew[e] * dinv[d];
    }
}

// ---------------- fused GCN: xw in LDS, gather from LDS, relu -> bf16 seq ----------------
// One block per bt (512 blocks x 1024 thr, ~134KB LDS, 1 block/CU).
// Phase 1: xw_lds[n][g] = sum_i x[bt][n][i] * w[t][i][g]   (x broadcast, w in LDS)
// Phase 2: seq[bt][n][g] = bf16(relu(sum_p nrm[p]*xw_lds[src[p]][g] + gb[t][g]))
__global__ __launch_bounds__(1024) void gcn_fused(const float* __restrict__ x,
                                                  const float* __restrict__ gw,
                                                  const float* __restrict__ gb,
                                                  const int* __restrict__ rowptr,
                                                  const int* __restrict__ csr_src,
                                                  const float* __restrict__ csr_nrm,
                                                  u16* __restrict__ seq) {
    __shared__ float xwlds[NN * NG];     // 128 KB
    __shared__ float wlds[NC * NG];      // 2 KB
    __shared__ int rplds[NN + 1];        // 4 KB
    int bt = blockIdx.x;
    int t = bt & 15;
    int tid = threadIdx.x;
    int g = tid & 31, grp = tid >> 5;    // 32 groups of 32 lanes

    for (int i = tid; i < NC * NG; i += 1024) wlds[i] = gw[t * NC * NG + i];
    for (int i = tid; i <= NN; i += 1024) rplds[i] = rowptr[i];
    __syncthreads();

    // phase 1: compute xw into LDS
    const float* xbt = x + (size_t)bt * NN * NC;
    for (int r = grp; r < NN; r += 32) {
        const float* xr = xbt + r * NC;
        float acc = 0.f;
#pragma unroll
        for (int i = 0; i < NC; ++i) acc += xr[i] * wlds[i * NG + g];
        xwlds[r * NG + g] = acc;
    }
    __syncthreads();

    // phase 2: gather + relu + bf16 store
    float bias = gb[t * NG + g];
    u16* seqbt = seq + (size_t)bt * NK;
    for (int n = grp; n < NN; n += 32) {
        int p0 = rplds[n], p1 = rplds[n + 1];
        float acc = 0.f;
        for (int p = p0; p < p1; ++p)
            acc += csr_nrm[p] * xwlds[csr_src[p] * NG + g];
        seqbt[n * NG + g] = f2bf(fmaxf(acc + bias, 0.f));
    }
}

// ---------------- w_ih0 fp32 -> bf16 ----------------
__global__ void wconv(const float4* __restrict__ in, ushort4* __restrict__ out, int n4) {
    for (int i = blockIdx.x * blockDim.x + threadIdx.x; i < n4; i += gridDim.x * blockDim.x) {
        float4 v = in[i];
        ushort4 o;
        o.x = f2bf(v.x); o.y = f2bf(v.y); o.z = f2bf(v.z); o.w = f2bf(v.w);
        out[i] = o;
    }
}

// ---------------- big GEMM: part[s] += seq(512xK) @ w16(2048xK)^T, split-K ----------------
__global__ __launch_bounds__(256) void gemm_bt(const u16* __restrict__ A,
                                               const u16* __restrict__ Bw,
                                               float* __restrict__ part) {
    __shared__ __align__(16) u16 As[128 * 64];
    __shared__ __align__(16) u16 Bs[128 * 64];
    int tid = threadIdx.x;
    int lane = tid & 63, wid = tid >> 6;
    int wr = wid >> 1, wc = wid & 1;
    int tm = blockIdx.x * 128, tn = blockIdx.y * 128;
    int s = blockIdx.z;
    int ks0 = s * 62 + (s < 4 ? s : 4);
    int ksn = (s < 4) ? 63 : 62;

    int srow = tid >> 3;     // 0..31
    int schunk = tid & 7;    // 0..7

    const u16* ga = A + (size_t)(tm + srow) * NK + (size_t)ks0 * 64 + schunk * 8;
    const u16* gb = Bw + (size_t)(tn + srow) * NK + (size_t)ks0 * 64 + schunk * 8;
    u16* la = As + srow * 64 + schunk * 8;
    u16* lb = Bs + srow * 64 + schunk * 8;

    f32x4 acc[4][4];
#pragma unroll
    for (int i = 0; i < 4; ++i)
#pragma unroll
        for (int j = 0; j < 4; ++j) acc[i][j] = (f32x4){0.f, 0.f, 0.f, 0.f};

    int fr = lane & 15, kq = lane >> 4;
    const u16* arow = As + (wr * 64 + fr) * 64 + kq * 8;
    const u16* brow = Bs + (wc * 64 + fr) * 64 + kq * 8;

    for (int ks = 0; ks < ksn; ++ks) {
        __syncthreads();
#pragma unroll
        for (int q = 0; q < 4; ++q) {
            GLOAD16(ga + (size_t)q * 32 * NK, la + q * 32 * 64);
            GLOAD16(gb + (size_t)q * 32 * NK, lb + q * 32 * 64);
        }
        __syncthreads();
#pragma unroll
        for (int kk = 0; kk < 2; ++kk) {
            bf16x8 af[4], bv[4];
#pragma unroll
            for (int fm = 0; fm < 4; ++fm) af[fm] = *(const bf16x8*)(arow + fm * 1024 + kk * 32);
#pragma unroll
            for (int fn = 0; fn < 4; ++fn) bv[fn] = *(const bf16x8*)(brow + fn * 1024 + kk * 32);
#pragma unroll
            for (int fm = 0; fm < 4; ++fm)
#pragma unroll
                for (int fn = 0; fn < 4; ++fn)
                    acc[fm][fn] = __builtin_amdgcn_mfma_f32_16x16x32_bf16(af[fm], bv[fn], acc[fm][fn], 0, 0, 0);
        }
        ga += 64; gb += 64;
    }

    int rq = lane >> 4;
    size_t base = (size_t)s * 512 * 2048;
#pragma unroll
    for (int fm = 0; fm < 4; ++fm)
#pragma unroll
        for (int fn = 0; fn < 4; ++fn)
#pragma unroll
            for (int rr = 0; rr < 4; ++rr) {
                int m = tm + wr * 64 + fm * 16 + rq * 4 + rr;
                int n = tn + wc * 64 + fn * 16 + (lane & 15);
                part[base + (size_t)m * 2048 + n] = acc[fm][fn][rr];
            }
}

// ---------------- reduce split-K partials + biases -> pre0p[s][row][b] ----------------
__global__ __launch_bounds__(256) void reduce_bias_p(const float* __restrict__ part,
                                                     const float* __restrict__ b_ih0,
                                                     const float* __restrict__ b_hh0,
                                                     float* __restrict__ pre0p) {
    int s = blockIdx.y;
    int r = blockIdx.x * 64 + (threadIdx.x & 63);
    int bq = threadIdx.x >> 6;  // 0..3
    float bias = b_ih0[r] + b_hh0[r];
#pragma unroll
    for (int b8 = 0; b8 < 8; ++b8) {
        int b = bq * 8 + b8;
        float acc = bias;
#pragma unroll
        for (int sk = 0; sk < 8; ++sk)
            acc += part[(size_t)sk * 1048576 + (size_t)(b * 16 + s) * 2048 + r];
        pre0p[((size_t)s * 2048 + r) * 32 + b] = acc;
    }
}

// ---------------- weight permute: frag-blocked bf16 Wbig[wg][rt][kt][lane][8] ----------------
__global__ __launch_bounds__(256) void wperm(const float* __restrict__ w_hh0,
                                             const float* __restrict__ w_ih1,
                                             const float* __restrict__ w_hh1,
                                             u16* __restrict__ Wbig) {
    int rt = blockIdx.x;   // 0..5
    int wg = blockIdx.y;   // 0..63
    int tid = threadIdx.x;
#pragma unroll
    for (int it = 0; it < 4; ++it) {
        int idx = it * 256 + tid;           // 0..1023
        int kt = idx >> 6, lane = idx & 63;
        int p = rt * 16 + (lane & 15);
        int gate = (p & 31) >> 3;
        int col = wg * 8 + (p & 7);
        const float* src;
        if (p < 32)      src = w_hh0 + (size_t)(gate * NH + col) * NH;
        else if (p < 64) src = w_ih1 + (size_t)(gate * NH + col) * NH;
        else             src = w_hh1 + (size_t)(gate * NH + col) * NH;
        int k0 = kt * 32 + (lane >> 4) * 8;
        float4 v0 = *(const float4*)(src + k0);
        float4 v1 = *(const float4*)(src + k0 + 4);
        u16x8 o;
        o[0] = f2bf(v0.x); o[1] = f2bf(v0.y); o[2] = f2bf(v0.z); o[3] = f2bf(v0.w);
        o[4] = f2bf(v1.x); o[5] = f2bf(v1.y); o[6] = f2bf(v1.z); o[7] = f2bf(v1.w);
        *(u16x8*)(Wbig + (((size_t)wg * 6 + rt) * 16 + kt) * 512 + lane * 8) = o;
    }
}

__global__ void init2(u16* h0, u16* h1, int* flags) {
    int i = blockIdx.x * 256 + threadIdx.x;
    if (i < 2 * BH) { h0[i] = 0; h1[i] = 0; }
    if (i < 1024) flags[i] = 0;
}

// ---------------- persistent MFMA LSTM: 64 WGs x 384 thr, weights in LDS ----------------
__global__ __launch_bounds__(LTH) void lstm2(const u16* __restrict__ Wbig,
                                             const float* __restrict__ pre0p,
                                             const float* __restrict__ b_ih1,
                                             const float* __restrict__ b_hh1,
                                             u16* __restrict__ h0buf,   // 2*BH bf16
                                             u16* __restrict__ h1buf,   // 2*BH bf16
                                             float* __restrict__ h1f,   // BH fp32 (final)
                                             int* __restrict__ flags) {
    __shared__ __align__(16) u16 Wlds[96 * 512];   // 96KB, frag-blocked [rt][kt][lane][8]
    __shared__ float G[96][33];                    // gate outputs, padded
    __shared__ float cst[2][8][32];                // c-state [layer][col][b]
    __shared__ u16 hst[2][8][32];                  // h bf16 staging
    int wg = blockIdx.x, tid = threadIdx.x;
    int wid = tid >> 6, lane = tid & 63;
    int grp = wid >> 1;

    // stage weights global->LDS (linear, 16 iters x 384 thr x 16B)
#pragma unroll
    for (int it = 0; it < 16; ++it)
        GLOAD16(Wbig + (size_t)wg * 49152 + it * 3072 + tid * 8, Wlds + it * 3072 + tid * 8);

    // init c-state
    if (tid < 512) ((float*)cst)[tid] = 0.f;

    // update-thread constants
    int uj = (tid >> 5) & 7, ub = tid & 31;
    int ucol = wg * 8 + uj;
    float bs0 = 0.f, bs1 = 0.f, bs2 = 0.f, bs3 = 0.f;
    if (tid < 256) {
        bs0 = b_ih1[ucol] + b_hh1[ucol];
        bs1 = b_ih1[NH + ucol] + b_hh1[NH + ucol];
        bs2 = b_ih1[2 * NH + ucol] + b_hh1[2 * NH + ucol];
        bs3 = b_ih1[3 * NH + ucol] + b_hh1[3 * NH + ucol];
    }
    __syncthreads();   // weights staged (barrier drains vmcnt), c ready

    const u16* wbase = Wlds + wid * 16 * 512 + lane * 8;

    for (int s = 0; s <= 16; ++s) {
        bool active = (grp == 0) ? (s < 16) : (s >= 1);
        if (active) {
            const u16* hb = (grp < 2) ? (h0buf + ((s & 1) ^ 1) * BH)
                                      : (h1buf + (s & 1) * BH);
            const u16* hp0 = hb + (lane & 15) * 512 + (lane >> 4) * 8;
            const u16* hp1 = hp0 + 16 * 512;
            f32x4 a0 = (f32x4){0.f, 0.f, 0.f, 0.f};
            f32x4 a1 = (f32x4){0.f, 0.f, 0.f, 0.f};
#pragma unroll
            for (int kt = 0; kt < 16; ++kt) {
                bf16x8 af = *(const bf16x8*)(wbase + kt * 512);
                bf16x8 b0 = *(const bf16x8*)(hp0 + kt * 32);
                bf16x8 b1 = *(const bf16x8*)(hp1 + kt * 32);
                a0 = __builtin_amdgcn_mfma_f32_16x16x32_bf16(af, b0, a0, 0, 0, 0);
                a1 = __builtin_amdgcn_mfma_f32_16x16x32_bf16(af, b1, a1, 0, 0, 0);
            }
            int r0 = wid * 16 + (lane >> 4) * 4;
#pragma unroll
            for (int rr = 0; rr < 4; ++rr) {
                G[r0 + rr][lane & 15] = a0[rr];
                G[r0 + rr][16 + (lane & 15)] = a1[rr];
            }
        }
        __syncthreads();

        if (tid < 256) {
            if (s < 16) {  // layer 0 update
                const float* pp = pre0p + (size_t)s * 2048 * 32 + ub;
                float gi = G[uj][ub]      + pp[(size_t)(ucol) * 32];
                float gf = G[8 + uj][ub]  + pp[(size_t)(NH + ucol) * 32];
                float gg = G[16 + uj][ub] + pp[(size_t)(2 * NH + ucol) * 32];
                float go = G[24 + uj][ub] + pp[(size_t)(3 * NH + ucol) * 32];
                float c = sigmoidf(gf) * cst[0][uj][ub] + sigmoidf(gi) * tanhf(gg);
                cst[0][uj][ub] = c;
                hst[0][uj][ub] = f2bf(sigmoidf(go) * tanhf(c));
            }
            if (s >= 1) {  // layer 1 update (t = s-1)
                float gi = G[32 + uj][ub] + G[64 + uj][ub] + bs0;
                float gf = G[40 + uj][ub] + G[72 + uj][ub] + bs1;
                float gg = G[48 + uj][ub] + G[80 + uj][ub] + bs2;
                float go = G[56 + uj][ub] + G[88 + uj][ub] + bs3;
                float c = sigmoidf(gf) * cst[1][uj][ub] + sigmoidf(gi) * tanhf(gg);
                cst[1][uj][ub] = c;
                float hv = sigmoidf(go) * tanhf(c);
                hst[1][uj][ub] = f2bf(hv);
                if (s == 16) h1f[ub * NH + ucol] = hv;
            }
        }
        __syncthreads();

        // pack h (wave 0): 16B per batch row
        if (tid < 32 && s < 16) {
            u16x8 v;
#pragma unroll
            for (int j = 0; j < 8; ++j) v[j] = hst[0][j][tid];
            *(u16x8*)(h0buf + (s & 1) * BH + tid * 512 + wg * 8) = v;
        }
        if (tid >= 32 && tid < 64 && s >= 1) {
            int b = tid - 32;
            u16x8 v;
#pragma unroll
            for (int j = 0; j < 8; ++j) v[j] = hst[1][j][b];
            *(u16x8*)(h1buf + ((s - 1) & 1) * BH + b * 512 + wg * 8) = v;
        }

        // ---- flag barrier ----
        __syncthreads();
        if (wid == 0) {
            __builtin_amdgcn_fence(__ATOMIC_RELEASE, "agent");  // drain wave0's h stores
            if (lane == 0) AT_STORE(&flags[wg * 16], s + 1);
            int target = s + 1;
            for (;;) {
                int v = AT_LOAD(&flags[lane * 16]);
                if (__all(v >= target)) break;
                __builtin_amdgcn_s_sleep(2);
            }
        }
        __builtin_amdgcn_fence(__ATOMIC_ACQUIRE, "agent");
        __syncthreads();
    }
}

// ---------------- projection from fp32 final h1 ----------------
__global__ __launch_bounds__(1024) void proj_k(const float* __restrict__ h1f,
                                               const float* __restrict__ proj_w,
                                               const float* __restrict__ proj_b,
                                               float* __restrict__ out) {
    __shared__ float pj[32][8][4];
    int tid = threadIdx.x;
    int b = tid >> 5, o = (tid >> 2) & 7, kq = tid & 3;
    const float4* hp = (const float4*)(h1f + (size_t)b * NH + kq * 128);
    const float4* wp = (const float4*)(proj_w + (size_t)o * NH + kq * 128);
    float acc = 0.f;
#pragma unroll 8
    for (int k = 0; k < 32; ++k) acc += dot4(hp[k], wp[k]);
    pj[b][o][kq] = acc;
    __syncthreads();
    if (tid < 256) {
        int bb = tid >> 3, oo = tid & 7;
        out[bb * 8 + oo] = pj[bb][oo][0] + pj[bb][oo][1] + pj[bb][oo][2] + pj[bb][oo][3] + proj_b[oo];
    }
}

extern "C" void kernel_launch(void* const* d_in, const int* in_sizes, int n_in,
                              void* d_out, int out_size, void* d_ws, size_t ws_size,
                              hipStream_t stream) {
    const float* x      = (const float*)d_in[0];
    const int*   ei     = (const int*)d_in[1];
    const float* ew     = (const float*)d_in[2];
    const float* gcn_w  = (const float*)d_in[3];
    const float* gcn_b  = (const float*)d_in[4];
    const float* w_ih0  = (const float*)d_in[5];
    const float* w_hh0  = (const float*)d_in[6];
    const float* b_ih0  = (const float*)d_in[7];
    const float* b_hh0  = (const float*)d_in[8];
    const float* w_ih1  = (const float*)d_in[9];
    const float* w_hh1  = (const float*)d_in[10];
    const float* b_ih1  = (const float*)d_in[11];
    const float* b_hh1  = (const float*)d_in[12];
    const float* proj_w = (const float*)d_in[13];
    const float* proj_b = (const float*)d_in[14];
    int E = in_sizes[2];

    char* ws = (char*)d_ws;
    size_t off = 0;
    u16* w16      = (u16*)(ws + off);  off += 131072000;         // 2048*32000 bf16
    float* part   = (float*)(ws + off);                          // 8*512*2048 f32
    u16* Wbig     = (u16*)part;        off += 65536000;          // aliases part (6.3MB, after reduce)
    u16* seq      = (u16*)(ws + off);  off += 32768000;          // 512*32000 bf16
    float* pre0p  = (float*)(ws + off); off += 4194304;          // [16][2048][32] f32
    u16* h0buf    = (u16*)(ws + off);  off += 2 * BH * 2;
    u16* h1buf    = (u16*)(ws + off);  off += 2 * BH * 2;
    float* h1f    = (float*)(ws + off); off += BH * 4;
    int* flags    = (int*)(ws + off);  off += 4096;
    int* rowptr   = (int*)(ws + off);  off += 4096;
    int* csr_src  = (int*)(ws + off);  off += 36864;
    float* csr_nrm = (float*)(ws + off); off += 36864;
    (void)ws_size; (void)n_in; (void)out_size;

    graph_prep<<<1, 1024, 0, stream>>>(ei, ew, E, rowptr, csr_src, csr_nrm);
    gcn_fused<<<512, 1024, 0, stream>>>(x, gcn_w, gcn_b, rowptr, csr_src, csr_nrm, seq);
    wconv<<<8192, 256, 0, stream>>>((const float4*)w_ih0, (ushort4*)w16, 16384000);
    gemm_bt<<<dim3(4, 16, 8), 256, 0, stream>>>(seq, w16, part);
    reduce_bias_p<<<dim3(32, 16), 256, 0, stream>>>(part, b_ih0, b_hh0, pre0p);
    // part is now consumed -> its region hosts Wbig
    wperm<<<dim3(6, 64), 256, 0, stream>>>(w_hh0, w_ih1, w_hh1, Wbig);
    init2<<<128, 256, 0, stream>>>(h0buf, h1buf, flags);

    lstm2<<<LWG, LTH, 0, stream>>>(Wbig, pre0p, b_ih1, b_hh1, h0buf, h1buf, h1f, flags);
    proj_k<<<1, 1024, 0, stream>>>(h1f, proj_w, proj_b, (float*)d_out);
}

// Round 7
// 506.978 us; speedup vs baseline: 3.8363x; 1.1854x over previous
//
#include <hip/hip_runtime.h>
#include <hip/hip_bf16.h>

typedef unsigned short u16;
typedef __bf16 bf16x8 __attribute__((ext_vector_type(8)));
typedef float f32x4 __attribute__((ext_vector_type(4)));
typedef unsigned short u16x8 __attribute__((ext_vector_type(8)));
typedef unsigned long long u64;

#define NB 32      // batch
#define NT 16      // time
#define NN 1000    // nodes
#define NC 16      // in feat
#define NG 32      // gcn out feat
#define NH 512     // hidden
#define NK 32000   // N*G
#define BH (NB*NH) // 16384
#define LWG 64     // lstm workgroups
#define LTH 384    // lstm threads (6 waves)

__device__ __forceinline__ u16 f2bf(float f) {
    unsigned int u = __float_as_uint(f);
    unsigned int r = u + 0x7FFFu + ((u >> 16) & 1u);
    return (u16)(r >> 16);
}

__device__ __forceinline__ float sigmoidf(float x) { return 1.f / (1.f + __expf(-x)); }

__device__ __forceinline__ float dot4(float4 a, float4 b) {
    return a.x * b.x + a.y * b.y + a.z * b.z + a.w * b.w;
}

#define AT_LOAD(p)    __hip_atomic_load((p), __ATOMIC_RELAXED, __HIP_MEMORY_SCOPE_AGENT)
#define AT_STORE(p,v) __hip_atomic_store((p), (v), __ATOMIC_RELAXED, __HIP_MEMORY_SCOPE_AGENT)

#define GLOAD16(g, l) __builtin_amdgcn_global_load_lds( \
    (const __attribute__((address_space(1))) void*)(g),  \
    (__attribute__((address_space(3))) void*)(l), 16, 0, 0)

// ---------------- graph prep: deg, norm, CSR by dst ----------------
__global__ void graph_prep(const int* __restrict__ ei, const float* __restrict__ ew, int E,
                           int* __restrict__ rowptr, int* __restrict__ csr_src,
                           float* __restrict__ csr_nrm) {
    __shared__ float degs[NN];
    __shared__ float dinv[NN];
    __shared__ int cnt[NN];
    __shared__ int rp[NN + 1];
    int tid = threadIdx.x;
    for (int n = tid; n < NN; n += 1024) { degs[n] = 0.f; cnt[n] = 0; }
    __syncthreads();
    for (int e = tid; e < E; e += 1024) {
        int d = ei[E + e];
        atomicAdd(&degs[d], ew[e]);
        atomicAdd(&cnt[d], 1);
    }
    __syncthreads();
    for (int n = tid; n < NN; n += 1024) {
        float d = degs[n];
        dinv[n] = d > 0.f ? rsqrtf(fmaxf(d, 1e-12f)) : 0.f;
    }
    __syncthreads();
    if (tid == 0) {
        int acc = 0;
        for (int n = 0; n < NN; ++n) { rp[n] = acc; acc += cnt[n]; }
        rp[NN] = acc;
    }
    __syncthreads();
    for (int n = tid; n <= NN; n += 1024) rowptr[n] = rp[n];
    for (int n = tid; n < NN; n += 1024) cnt[n] = 0;
    __syncthreads();
    for (int e = tid; e < E; e += 1024) {
        int d = ei[E + e], s = ei[e];
        int pos = rp[d] + atomicAdd(&cnt[d], 1);
        csr_src[pos] = s;
        csr_nrm[pos] = dinv[s] * ew[e] * dinv[d];
    }
}

// ---------------- fused GCN: xw in LDS, gather from LDS, relu -> bf16 seq ----------------
__global__ __launch_bounds__(1024) void gcn_fused(const float* __restrict__ x,
                                                  const float* __restrict__ gw,
                                                  const float* __restrict__ gb,
                                                  const int* __restrict__ rowptr,
                                                  const int* __restrict__ csr_src,
                                                  const float* __restrict__ csr_nrm,
                                                  u16* __restrict__ seq) {
    __shared__ float xwlds[NN * NG];     // 128 KB
    __shared__ float wlds[NC * NG];      // 2 KB
    __shared__ int rplds[NN + 1];        // 4 KB
    int bt = blockIdx.x;
    int t = bt & 15;
    int tid = threadIdx.x;
    int g = tid & 31, grp = tid >> 5;    // 32 groups of 32 lanes

    for (int i = tid; i < NC * NG; i += 1024) wlds[i] = gw[t * NC * NG + i];
    for (int i = tid; i <= NN; i += 1024) rplds[i] = rowptr[i];
    __syncthreads();

    const float* xbt = x + (size_t)bt * NN * NC;
    for (int r = grp; r < NN; r += 32) {
        const float* xr = xbt + r * NC;
        float acc = 0.f;
#pragma unroll
        for (int i = 0; i < NC; ++i) acc += xr[i] * wlds[i * NG + g];
        xwlds[r * NG + g] = acc;
    }
    __syncthreads();

    float bias = gb[t * NG + g];
    u16* seqbt = seq + (size_t)bt * NK;
    for (int n = grp; n < NN; n += 32) {
        int p0 = rplds[n], p1 = rplds[n + 1];
        float acc = 0.f;
        for (int p = p0; p < p1; ++p)
            acc += csr_nrm[p] * xwlds[csr_src[p] * NG + g];
        seqbt[n * NG + g] = f2bf(fmaxf(acc + bias, 0.f));
    }
}

// ---------------- w_ih0 fp32 -> bf16 ----------------
__global__ void wconv(const float4* __restrict__ in, ushort4* __restrict__ out, int n4) {
    for (int i = blockIdx.x * blockDim.x + threadIdx.x; i < n4; i += gridDim.x * blockDim.x) {
        float4 v = in[i];
        ushort4 o;
        o.x = f2bf(v.x); o.y = f2bf(v.y); o.z = f2bf(v.z); o.w = f2bf(v.w);
        out[i] = o;
    }
}

// ---------------- big GEMM: part[s] += seq(512xK) @ w16(2048xK)^T, split-K ----------------
__global__ __launch_bounds__(256) void gemm_bt(const u16* __restrict__ A,
                                               const u16* __restrict__ Bw,
                                               float* __restrict__ part) {
    __shared__ __align__(16) u16 As[128 * 64];
    __shared__ __align__(16) u16 Bs[128 * 64];
    int tid = threadIdx.x;
    int lane = tid & 63, wid = tid >> 6;
    int wr = wid >> 1, wc = wid & 1;
    int tm = blockIdx.x * 128, tn = blockIdx.y * 128;
    int s = blockIdx.z;
    int ks0 = s * 62 + (s < 4 ? s : 4);
    int ksn = (s < 4) ? 63 : 62;

    int srow = tid >> 3;     // 0..31
    int schunk = tid & 7;    // 0..7

    const u16* ga = A + (size_t)(tm + srow) * NK + (size_t)ks0 * 64 + schunk * 8;
    const u16* gb = Bw + (size_t)(tn + srow) * NK + (size_t)ks0 * 64 + schunk * 8;
    u16* la = As + srow * 64 + schunk * 8;
    u16* lb = Bs + srow * 64 + schunk * 8;

    f32x4 acc[4][4];
#pragma unroll
    for (int i = 0; i < 4; ++i)
#pragma unroll
        for (int j = 0; j < 4; ++j) acc[i][j] = (f32x4){0.f, 0.f, 0.f, 0.f};

    int fr = lane & 15, kq = lane >> 4;
    const u16* arow = As + (wr * 64 + fr) * 64 + kq * 8;
    const u16* brow = Bs + (wc * 64 + fr) * 64 + kq * 8;

    for (int ks = 0; ks < ksn; ++ks) {
        __syncthreads();
#pragma unroll
        for (int q = 0; q < 4; ++q) {
            GLOAD16(ga + (size_t)q * 32 * NK, la + q * 32 * 64);
            GLOAD16(gb + (size_t)q * 32 * NK, lb + q * 32 * 64);
        }
        __syncthreads();
#pragma unroll
        for (int kk = 0; kk < 2; ++kk) {
            bf16x8 af[4], bv[4];
#pragma unroll
            for (int fm = 0; fm < 4; ++fm) af[fm] = *(const bf16x8*)(arow + fm * 1024 + kk * 32);
#pragma unroll
            for (int fn = 0; fn < 4; ++fn) bv[fn] = *(const bf16x8*)(brow + fn * 1024 + kk * 32);
#pragma unroll
            for (int fm = 0; fm < 4; ++fm)
#pragma unroll
                for (int fn = 0; fn < 4; ++fn)
                    acc[fm][fn] = __builtin_amdgcn_mfma_f32_16x16x32_bf16(af[fm], bv[fn], acc[fm][fn], 0, 0, 0);
        }
        ga += 64; gb += 64;
    }

    int rq = lane >> 4;
    size_t base = (size_t)s * 512 * 2048;
#pragma unroll
    for (int fm = 0; fm < 4; ++fm)
#pragma unroll
        for (int fn = 0; fn < 4; ++fn)
#pragma unroll
            for (int rr = 0; rr < 4; ++rr) {
                int m = tm + wr * 64 + fm * 16 + rq * 4 + rr;
                int n = tn + wc * 64 + fn * 16 + (lane & 15);
                part[base + (size_t)m * 2048 + n] = acc[fm][fn][rr];
            }
}

// ---------------- reduce split-K partials + biases -> pre0p[s][row][b] ----------------
__global__ __launch_bounds__(256) void reduce_bias_p(const float* __restrict__ part,
                                                     const float* __restrict__ b_ih0,
                                                     const float* __restrict__ b_hh0,
                                                     float* __restrict__ pre0p) {
    int s = blockIdx.y;
    int r = blockIdx.x * 64 + (threadIdx.x & 63);
    int bq = threadIdx.x >> 6;  // 0..3
    float bias = b_ih0[r] + b_hh0[r];
#pragma unroll
    for (int b8 = 0; b8 < 8; ++b8) {
        int b = bq * 8 + b8;
        float acc = bias;
#pragma unroll
        for (int sk = 0; sk < 8; ++sk)
            acc += part[(size_t)sk * 1048576 + (size_t)(b * 16 + s) * 2048 + r];
        pre0p[((size_t)s * 2048 + r) * 32 + b] = acc;
    }
}

// ---------------- weight permute: frag-blocked bf16 Wbig[wg][rt][kt][lane][8] ----------------
__global__ __launch_bounds__(256) void wperm(const float* __restrict__ w_hh0,
                                             const float* __restrict__ w_ih1,
                                             const float* __restrict__ w_hh1,
                                             u16* __restrict__ Wbig) {
    int rt = blockIdx.x;   // 0..5
    int wg = blockIdx.y;   // 0..63
    int tid = threadIdx.x;
#pragma unroll
    for (int it = 0; it < 4; ++it) {
        int idx = it * 256 + tid;           // 0..1023
        int kt = idx >> 6, lane = idx & 63;
        int p = rt * 16 + (lane & 15);
        int gate = (p & 31) >> 3;
        int col = wg * 8 + (p & 7);
        const float* src;
        if (p < 32)      src = w_hh0 + (size_t)(gate * NH + col) * NH;
        else if (p < 64) src = w_ih1 + (size_t)(gate * NH + col) * NH;
        else             src = w_hh1 + (size_t)(gate * NH + col) * NH;
        int k0 = kt * 32 + (lane >> 4) * 8;
        float4 v0 = *(const float4*)(src + k0);
        float4 v1 = *(const float4*)(src + k0 + 4);
        u16x8 o;
        o[0] = f2bf(v0.x); o[1] = f2bf(v0.y); o[2] = f2bf(v0.z); o[3] = f2bf(v0.w);
        o[4] = f2bf(v1.x); o[5] = f2bf(v1.y); o[6] = f2bf(v1.z); o[7] = f2bf(v1.w);
        *(u16x8*)(Wbig + (((size_t)wg * 6 + rt) * 16 + kt) * 512 + lane * 8) = o;
    }
}

__global__ void init2(u16* h0, u16* h1, int* flags) {
    int i = blockIdx.x * 256 + threadIdx.x;
    if (i < 2 * BH) { h0[i] = 0; h1[i] = 0; }
    if (i < 1024) flags[i] = 0;
}

// ---------------- persistent MFMA LSTM: 64 WGs x 384 thr ----------------
// A-frags (weights) in REGISTERS (step-invariant, 64 VGPR). Per step, all 6 waves
// cooperatively stage h0prev+h1prev (64KB) into LDS via coalesced agent-atomic u64
// loads (cache-bypassing => coherent without fences); MFMA B-frags from LDS
// (1040B-padded rows => 2-way bank alias only). h published via write-through
// agent-atomic u64 stores + vmcnt(0) + flag store; readers poll 64 flags. NO fences.
__global__ __launch_bounds__(LTH) void lstm2(const u16* __restrict__ Wbig,
                                             const float* __restrict__ pre0p,
                                             const float* __restrict__ b_ih1,
                                             const float* __restrict__ b_hh1,
                                             u16* __restrict__ h0buf,   // 2*BH bf16
                                             u16* __restrict__ h1buf,   // 2*BH bf16
                                             float* __restrict__ h1f,   // BH fp32 (final)
                                             int* __restrict__ flags) {
    __shared__ __align__(16) u16 hA0[32 * 520];    // 33.3 KB, 1040B rows
    __shared__ __align__(16) u16 hA1[32 * 520];
    __shared__ float G[96][33];                    // gate outputs, padded
    __shared__ float cst[2][8][32];                // c-state [layer][col][b]
    __shared__ u16 hst[2][8][32];                  // h bf16 staging
    int wg = blockIdx.x, tid = threadIdx.x;
    int wid = tid >> 6, lane = tid & 63;
    int grp = wid >> 1;

    // A-frags into registers (coalesced, once)
    bf16x8 af[16];
    const u16* wsrc = Wbig + (size_t)wg * 49152 + wid * 8192 + lane * 8;
#pragma unroll
    for (int kt = 0; kt < 16; ++kt) af[kt] = *(const bf16x8*)(wsrc + kt * 512);

    if (tid < 512) ((float*)cst)[tid] = 0.f;

    // update-thread constants
    int uj = (tid >> 5) & 7, ub = tid & 31;
    int ucol = wg * 8 + uj;
    float bs0 = 0.f, bs1 = 0.f, bs2 = 0.f, bs3 = 0.f;
    if (tid < 256) {
        bs0 = b_ih1[ucol] + b_hh1[ucol];
        bs1 = b_ih1[NH + ucol] + b_hh1[NH + ucol];
        bs2 = b_ih1[2 * NH + ucol] + b_hh1[2 * NH + ucol];
        bs3 = b_ih1[3 * NH + ucol] + b_hh1[3 * NH + ucol];
    }
    __syncthreads();

    for (int s = 0; s <= 16; ++s) {
        // ---- cooperative coherent stage: h0prev -> hA0 (rows 0..31), h1prev -> hA1 ----
        for (int r = wid; r < 64; r += 6) {
            const u64* src = (r < 32)
                ? (const u64*)(h0buf + ((s & 1) ^ 1) * BH + r * 512)
                : (const u64*)(h1buf + (s & 1) * BH + (r - 32) * 512);
            u16* dst = (r < 32) ? (hA0 + r * 520) : (hA1 + (r - 32) * 520);
            u64 v0 = AT_LOAD(src + lane);
            u64 v1 = AT_LOAD(src + 64 + lane);
            *(u64*)(dst + lane * 4) = v0;
            *(u64*)(dst + 256 + lane * 4) = v1;
        }
        // prefetch pre0p for this step (plain loads; caches stay valid — no fences)
        float up0 = 0.f, up1 = 0.f, up2 = 0.f, up3 = 0.f;
        if (tid < 256 && s < 16) {
            const float* pp = pre0p + (size_t)s * 2048 * 32 + ub;
            up0 = pp[(size_t)ucol * 32];
            up1 = pp[((size_t)NH + ucol) * 32];
            up2 = pp[((size_t)2 * NH + ucol) * 32];
            up3 = pp[((size_t)3 * NH + ucol) * 32];
        }
        __syncthreads();   // stage complete

        // ---- MFMA: A from registers, B from LDS ----
        bool active = (grp == 0) ? (s < 16) : (s >= 1);
        if (active) {
            const u16* hA = (grp < 2) ? hA0 : hA1;
            const u16* hp = hA + (lane & 15) * 520 + (lane >> 4) * 8;
            f32x4 a0 = (f32x4){0.f, 0.f, 0.f, 0.f};
            f32x4 a1 = (f32x4){0.f, 0.f, 0.f, 0.f};
#pragma unroll
            for (int kt = 0; kt < 16; ++kt) {
                bf16x8 b0 = *(const bf16x8*)(hp + kt * 32);
                bf16x8 b1 = *(const bf16x8*)(hp + 16 * 520 + kt * 32);
                a0 = __builtin_amdgcn_mfma_f32_16x16x32_bf16(af[kt], b0, a0, 0, 0, 0);
                a1 = __builtin_amdgcn_mfma_f32_16x16x32_bf16(af[kt], b1, a1, 0, 0, 0);
            }
            int r0 = wid * 16 + (lane >> 4) * 4;
#pragma unroll
            for (int rr = 0; rr < 4; ++rr) {
                G[r0 + rr][lane & 15] = a0[rr];
                G[r0 + rr][16 + (lane & 15)] = a1[rr];
            }
        }
        __syncthreads();

        // ---- gate updates ----
        if (tid < 256) {
            if (s < 16) {  // layer 0
                float gi = G[uj][ub] + up0;
                float gf = G[8 + uj][ub] + up1;
                float gg = G[16 + uj][ub] + up2;
                float go = G[24 + uj][ub] + up3;
                float c = sigmoidf(gf) * cst[0][uj][ub] + sigmoidf(gi) * tanhf(gg);
                cst[0][uj][ub] = c;
                hst[0][uj][ub] = f2bf(sigmoidf(go) * tanhf(c));
            }
            if (s >= 1) {  // layer 1 (t = s-1)
                float gi = G[32 + uj][ub] + G[64 + uj][ub] + bs0;
                float gf = G[40 + uj][ub] + G[72 + uj][ub] + bs1;
                float gg = G[48 + uj][ub] + G[80 + uj][ub] + bs2;
                float go = G[56 + uj][ub] + G[88 + uj][ub] + bs3;
                float c = sigmoidf(gf) * cst[1][uj][ub] + sigmoidf(gi) * tanhf(gg);
                cst[1][uj][ub] = c;
                float hv = sigmoidf(go) * tanhf(c);
                hst[1][uj][ub] = f2bf(hv);
                if (s == 16) h1f[ub * NH + ucol] = hv;
            }
        }
        __syncthreads();

        // ---- publish (write-through atomics) + flag barrier, no fences ----
        if (s < 16) {
            if (wid == 0) {
                if (lane < 32) {
                    union { u16 a[8]; u64 q[2]; } v;
#pragma unroll
                    for (int j = 0; j < 8; ++j) v.a[j] = hst[0][j][lane];
                    u64* d = (u64*)(h0buf + (s & 1) * BH + lane * 512 + wg * 8);
                    AT_STORE(d, v.q[0]); AT_STORE(d + 1, v.q[1]);
                } else if (s >= 1) {
                    int b = lane - 32;
                    union { u16 a[8]; u64 q[2]; } v;
#pragma unroll
                    for (int j = 0; j < 8; ++j) v.a[j] = hst[1][j][b];
                    u64* d = (u64*)(h1buf + ((s - 1) & 1) * BH + b * 512 + wg * 8);
                    AT_STORE(d, v.q[0]); AT_STORE(d + 1, v.q[1]);
                }
                asm volatile("s_waitcnt vmcnt(0)" ::: "memory");
                if (lane == 0) AT_STORE(&flags[wg * 16], s + 1);
                int target = s + 1;
                for (;;) {
                    int v = AT_LOAD(&flags[lane * 16]);
                    if (__all(v >= target)) break;
                    __builtin_amdgcn_s_sleep(2);
                }
            }
            __syncthreads();
        }
    }
}

// ---------------- projection from fp32 final h1 ----------------
__global__ __launch_bounds__(1024) void proj_k(const float* __restrict__ h1f,
                                               const float* __restrict__ proj_w,
                                               const float* __restrict__ proj_b,
                                               float* __restrict__ out) {
    __shared__ float pj[32][8][4];
    int tid = threadIdx.x;
    int b = tid >> 5, o = (tid >> 2) & 7, kq = tid & 3;
    const float4* hp = (const float4*)(h1f + (size_t)b * NH + kq * 128);
    const float4* wp = (const float4*)(proj_w + (size_t)o * NH + kq * 128);
    float acc = 0.f;
#pragma unroll 8
    for (int k = 0; k < 32; ++k) acc += dot4(hp[k], wp[k]);
    pj[b][o][kq] = acc;
    __syncthreads();
    if (tid < 256) {
        int bb = tid >> 3, oo = tid & 7;
        out[bb * 8 + oo] = pj[bb][oo][0] + pj[bb][oo][1] + pj[bb][oo][2] + pj[bb][oo][3] + proj_b[oo];
    }
}

extern "C" void kernel_launch(void* const* d_in, const int* in_sizes, int n_in,
                              void* d_out, int out_size, void* d_ws, size_t ws_size,
                              hipStream_t stream) {
    const float* x      = (const float*)d_in[0];
    const int*   ei     = (const int*)d_in[1];
    const float* ew     = (const float*)d_in[2];
    const float* gcn_w  = (const float*)d_in[3];
    const float* gcn_b  = (const float*)d_in[4];
    const float* w_ih0  = (const float*)d_in[5];
    const float* w_hh0  = (const float*)d_in[6];
    const float* b_ih0  = (const float*)d_in[7];
    const float* b_hh0  = (const float*)d_in[8];
    const float* w_ih1  = (const float*)d_in[9];
    const float* w_hh1  = (const float*)d_in[10];
    const float* b_ih1  = (const float*)d_in[11];
    const float* b_hh1  = (const float*)d_in[12];
    const float* proj_w = (const float*)d_in[13];
    const float* proj_b = (const float*)d_in[14];
    int E = in_sizes[2];

    char* ws = (char*)d_ws;
    size_t off = 0;
    u16* w16      = (u16*)(ws + off);  off += 131072000;         // 2048*32000 bf16
    float* part   = (float*)(ws + off);                          // 8*512*2048 f32
    u16* Wbig     = (u16*)part;        off += 65536000;          // aliases part (6.3MB, after reduce)
    u16* seq      = (u16*)(ws + off);  off += 32768000;          // 512*32000 bf16
    float* pre0p  = (float*)(ws + off); off += 4194304;          // [16][2048][32] f32
    u16* h0buf    = (u16*)(ws + off);  off += 2 * BH * 2;
    u16* h1buf    = (u16*)(ws + off);  off += 2 * BH * 2;
    float* h1f    = (float*)(ws + off); off += BH * 4;
    int* flags    = (int*)(ws + off);  off += 4096;
    int* rowptr   = (int*)(ws + off);  off += 4096;
    int* csr_src  = (int*)(ws + off);  off += 36864;
    float* csr_nrm = (float*)(ws + off); off += 36864;
    (void)ws_size; (void)n_in; (void)out_size;

    graph_prep<<<1, 1024, 0, stream>>>(ei, ew, E, rowptr, csr_src, csr_nrm);
    gcn_fused<<<512, 1024, 0, stream>>>(x, gcn_w, gcn_b, rowptr, csr_src, csr_nrm, seq);
    wconv<<<8192, 256, 0, stream>>>((const float4*)w_ih0, (ushort4*)w16, 16384000);
    gemm_bt<<<dim3(4, 16, 8), 256, 0, stream>>>(seq, w16, part);
    reduce_bias_p<<<dim3(32, 16), 256, 0, stream>>>(part, b_ih0, b_hh0, pre0p);
    // part is now consumed -> its region hosts Wbig
    wperm<<<dim3(6, 64), 256, 0, stream>>>(w_hh0, w_ih1, w_hh1, Wbig);
    init2<<<128, 256, 0, stream>>>(h0buf, h1buf, flags);

    lstm2<<<LWG, LTH, 0, stream>>>(Wbig, pre0p, b_ih1, b_hh1, h0buf, h1buf, h1f, flags);
    proj_k<<<1, 1024, 0, stream>>>(h1f, proj_w, proj_b, (float*)d_out);
}